// Round 10
// baseline (280.505 us; speedup 1.0000x reference)
//
#include <hip/hip_runtime.h>
#include <hip/hip_bf16.h>

#define NN 100000
#define NE 1600000
#define FIN 512
#define FH 32
#define FC 16
#define SCAN_B 1024
#define NBLK ((NN + SCAN_B - 1) / SCAN_B)   // 98
#define NCB ((NE / 4 + 255) / 256)          // 1563 fill blocks
#define M_SL 64                             // edge slices (one hist block each)
#define SLICE (NE / M_SL)                   // 25000 edges/slice
#define QSL (SLICE / 4)                     // 6250 quads/slice
#define PSZ 8192                            // bins per pass (32 KB LDS)
#define NP ((NN + PSZ - 1) / PSZ)           // 13 passes
#define NGB1 ((NN + 63) / 64)               // 1563 MFMA gemm blocks
#define SCALE_B ((NN * FH / 4 + SCAN_B - 1) / SCAN_B)  // 782

typedef __attribute__((ext_vector_type(8))) short bf16x8;
typedef __attribute__((ext_vector_type(4))) float f32x4;

__device__ inline unsigned short f2bf(float f) {
    unsigned u = __float_as_uint(f);
    return (unsigned short)((u + 0x7FFFu + ((u >> 16) & 1u)) >> 16);  // RNE
}

// ---------------- prep: W1 -> bf16, pre-swizzled to B-fragment order ----------------

__global__ __launch_bounds__(256) void k_prep(const float* __restrict__ W1,
                                              unsigned short* __restrict__ wbuf) {
    for (int idx = threadIdx.x; idx < 16 * 2 * 64; idx += 256) {
        int s = idx >> 7;
        int t = (idx >> 6) & 1;
        int l = idx & 63;
        int k0 = s * 32 + (l >> 4) * 8;
        int c = t * 16 + (l & 15);
        bf16x8 w;
#pragma unroll
        for (int i = 0; i < 8; ++i) w[i] = (short)f2bf(W1[(size_t)(k0 + i) * FH + c]);
        *(bf16x8*)(wbuf + (size_t)idx * 8) = w;
    }
}

// ---------------- fused: multi-pass LDS hist (per-slice block)  +  MFMA GEMM1 ----------------
// blocks [0, M_SL): slice m; loops over 13 node-partitions, slice stays L2-resident.
// blocks [M_SL, M_SL+NGB1): bf16 MFMA GEMM h1 = x @ W1 (64 nodes/block).

__global__ __launch_bounds__(256) void k_hist_gemm1(const int* __restrict__ col,
                                                    unsigned char* __restrict__ ghist,
                                                    unsigned char* __restrict__ rank,
                                                    const float* __restrict__ x,
                                                    const unsigned short* __restrict__ wbuf,
                                                    float* __restrict__ h1) {
    __shared__ int sh[PSZ];  // 32 KB; gemm path reuses as bf16 W store

    if (blockIdx.x < M_SL) {
        int m = blockIdx.x;
        const int4* c4p = (const int4*)(col + m * SLICE);
        for (int p = 0; p < NP; ++p) {
            int base = p * PSZ;
            int nb = min(PSZ, NN - base);
            for (int i = threadIdx.x; i < nb; i += 256) sh[i] = 0;
            __syncthreads();
            for (int it = 0; it < (QSL + 255) / 256; ++it) {
                int q = it * 256 + threadIdx.x;
                if (q < QSL) {
                    int4 c4 = c4p[q];
                    int e = m * SLICE + q * 4;
                    int cc[4] = {c4.x, c4.y, c4.z, c4.w};
#pragma unroll
                    for (int u = 0; u < 4; ++u) {
                        int d = cc[u] - base;
                        if ((unsigned)d < (unsigned)nb) {
                            int lr = atomicAdd(&sh[d], 1);
                            rank[e + u] = (unsigned char)lr;
                        }
                    }
                }
            }
            __syncthreads();
            for (int i = threadIdx.x; i < nb; i += 256)
                ghist[(size_t)m * NN + base + i] = (unsigned char)sh[i];
            __syncthreads();
        }
        return;
    }

    // ---- MFMA GEMM1 ----
    unsigned short* lb = (unsigned short*)sh;
    for (int i = threadIdx.x; i < 2048; i += 256)
        ((int4*)lb)[i] = ((const int4*)wbuf)[i];  // coalesced 32 KB stage
    __syncthreads();

    int wave = threadIdx.x >> 6;
    int lane = threadIdx.x & 63;
    int rowbase = (blockIdx.x - M_SL) * 64 + wave * 16;
    int arow = rowbase + (lane & 15);
    int arowc = min(arow, NN - 1);
    int kgrp = (lane >> 4) * 8;

    f32x4 acc0 = {0.f, 0.f, 0.f, 0.f};
    f32x4 acc1 = {0.f, 0.f, 0.f, 0.f};
    const float* xrow = x + (size_t)arowc * FIN + kgrp;

    for (int sg = 0; sg < 16; sg += 4) {
        float4 av[8];
#pragma unroll
        for (int u = 0; u < 4; ++u) {
            av[2 * u]     = *(const float4*)(xrow + (sg + u) * 32);
            av[2 * u + 1] = *(const float4*)(xrow + (sg + u) * 32 + 4);
        }
#pragma unroll
        for (int u = 0; u < 4; ++u) {
            const float* s0 = (const float*)&av[2 * u];
            const float* s1 = (const float*)&av[2 * u + 1];
            bf16x8 af;
            af[0] = (short)f2bf(s0[0]); af[1] = (short)f2bf(s0[1]);
            af[2] = (short)f2bf(s0[2]); af[3] = (short)f2bf(s0[3]);
            af[4] = (short)f2bf(s1[0]); af[5] = (short)f2bf(s1[1]);
            af[6] = (short)f2bf(s1[2]); af[7] = (short)f2bf(s1[3]);
            int s = sg + u;
            bf16x8 b0 = *(const bf16x8*)(lb + ((size_t)(s * 2 + 0) * 64 + lane) * 8);
            bf16x8 b1 = *(const bf16x8*)(lb + ((size_t)(s * 2 + 1) * 64 + lane) * 8);
            acc0 = __builtin_amdgcn_mfma_f32_16x16x32_bf16(af, b0, acc0, 0, 0, 0);
            acc1 = __builtin_amdgcn_mfma_f32_16x16x32_bf16(af, b1, acc1, 0, 0, 0);
        }
    }

    int crow = rowbase + (lane >> 4) * 4;
    int ccol = lane & 15;
#pragma unroll
    for (int r = 0; r < 4; ++r) {
        if (crow + r < NN) {
            h1[(size_t)(crow + r) * FH + ccol] = acc0[r];
            h1[(size_t)(crow + r) * FH + 16 + ccol] = acc1[r];
        }
    }
}

// ---------------- per-node slice-scan: ghist -> per-slice prefix; cnt, dis, part ----------------

__global__ __launch_bounds__(SCAN_B) void k_xscan(unsigned char* __restrict__ ghist,
                                                  int* __restrict__ cnt,
                                                  float* __restrict__ dis,
                                                  int* __restrict__ part) {
    __shared__ int s[SCAN_B];
    int c = blockIdx.x * SCAN_B + threadIdx.x;
    int sum = 0;
    if (c < NN) {
        for (int m = 0; m < M_SL; ++m) {
            size_t idx = (size_t)m * NN + c;
            int t = ghist[idx];
            ghist[idx] = (unsigned char)sum;  // exclusive per-slice prefix
            sum += t;
        }
        cnt[c] = sum;
        dis[c] = rsqrtf((float)sum + 1.0f);  // +1 self-loop
    }
    s[threadIdx.x] = sum;
    __syncthreads();
    for (int st = SCAN_B / 2; st > 0; st >>= 1) {
        if (threadIdx.x < st) s[threadIdx.x] += s[threadIdx.x + st];
        __syncthreads();
    }
    if (threadIdx.x == 0) part[blockIdx.x] = s[0];
}

// ---------------- scan of partials ----------------

__global__ __launch_bounds__(128) void k_scanpart(int* __restrict__ part) {
    __shared__ int s[128];
    int t = threadIdx.x;
    int v = (t < NBLK) ? part[t] : 0;
    s[t] = v;
    __syncthreads();
    for (int st = 1; st < 128; st <<= 1) {
        int a = (t >= st) ? s[t - st] : 0;
        __syncthreads();
        s[t] += a;
        __syncthreads();
    }
    if (t < NBLK) part[t] = s[t] - v;  // exclusive
}

// ---------------- fused: node-offset scan  +  h1s = h1 * dis[node] ----------------

__global__ __launch_bounds__(SCAN_B) void k_scan_scale(const int* __restrict__ cnt,
                                                       const int* __restrict__ part,
                                                       int* __restrict__ off,
                                                       const float4* __restrict__ h1,
                                                       float4* __restrict__ h1s,
                                                       const float* __restrict__ dis) {
    __shared__ int s[SCAN_B];
    int bid = blockIdx.x;
    if (bid < NBLK) {
        int i = bid * SCAN_B + threadIdx.x;
        int v = (i < NN) ? cnt[i] : 0;
        s[threadIdx.x] = v;
        __syncthreads();
        for (int st = 1; st < SCAN_B; st <<= 1) {
            int add = (threadIdx.x >= st) ? s[threadIdx.x - st] : 0;
            __syncthreads();
            s[threadIdx.x] += add;
            __syncthreads();
        }
        if (i < NN) off[i] = part[bid] + s[threadIdx.x] - v;  // exclusive
        if (i == NN - 1) off[NN] = part[bid] + s[threadIdx.x];
    } else {
        int i4 = (bid - NBLK) * SCAN_B + threadIdx.x;
        if (i4 < NN * FH / 4) {
            float4 v = h1[i4];
            float d = dis[i4 >> 3];
            h1s[i4] = make_float4(v.x * d, v.y * d, v.z * d, v.w * d);
        }
    }
}

// ---------------- CSR fill: atomic-free, slot = off[c] + ghist[m][c] + rank ----------------

__global__ void k_fill(const int* __restrict__ row, const int* __restrict__ col,
                       const unsigned char* __restrict__ rank,
                       const int* __restrict__ off,
                       const unsigned char* __restrict__ ghist,
                       int* __restrict__ esrc) {
    int i = blockIdx.x * blockDim.x + threadIdx.x;  // global quad index
    if (i >= NE / 4) return;
    int m = i / QSL;  // slice
    int4 r4 = ((const int4*)row)[i];
    int4 c4 = ((const int4*)col)[i];
    uchar4 rk4 = ((const uchar4*)rank)[i];
    int rr[4] = {r4.x, r4.y, r4.z, r4.w};
    int cc[4] = {c4.x, c4.y, c4.z, c4.w};
    int rk[4] = {rk4.x, rk4.y, rk4.z, rk4.w};
    int o4[4], bp[4];
#pragma unroll
    for (int u = 0; u < 4; ++u) o4[u] = off[cc[u]];
#pragma unroll
    for (int u = 0; u < 4; ++u) bp[u] = ghist[(size_t)m * NN + cc[u]];
#pragma unroll
    for (int u = 0; u < 4; ++u) esrc[o4[u] + bp[u] + rk[u]] = rr[u];
}

// ---------------- gather1 + relu + GEMM2 fused: h2s = relu(...)@W2 * dis ----------------
// 8 nodes/block, 32 lanes/node

__global__ __launch_bounds__(256) void k_gather1g2(const int* __restrict__ off,
                                                   const int* __restrict__ esrc,
                                                   const float* __restrict__ h1s,
                                                   const float* __restrict__ dis,
                                                   const float* __restrict__ b1,
                                                   const float* __restrict__ W2,
                                                   float* __restrict__ h2s) {
    __shared__ float w2l[FH * FC];     // 2 KB
    __shared__ float hrl[8][FH + 1];   // padded: no bank conflict in dot loop
    for (int i = threadIdx.x; i < FH * FC; i += 256) w2l[i] = W2[i];

    int ng = threadIdx.x >> 5;
    int f = threadIdx.x & 31;
    int g = blockIdx.x * 8 + ng;
    int s0 = off[g], s1 = off[g + 1];
    float acc = 0.0f, acc2 = 0.0f;
    int i = s0;
    for (; i + 1 < s1; i += 2) {
        int r0 = esrc[i], r1 = esrc[i + 1];
        acc += h1s[(size_t)r0 * FH + f];
        acc2 += h1s[(size_t)r1 * FH + f];
    }
    if (i < s1) acc += h1s[(size_t)esrc[i] * FH + f];
    acc += acc2 + h1s[(size_t)g * FH + f];
    float v = dis[g] * acc + b1[f];
    hrl[ng][f] = v > 0.0f ? v : 0.0f;
    __syncthreads();

    if (threadIdx.x < 128) {
        int ng2 = threadIdx.x >> 4;
        int j = threadIdx.x & 15;
        int g2 = blockIdx.x * 8 + ng2;
        float s = 0.0f;
#pragma unroll
        for (int k = 0; k < FH; ++k) s += hrl[ng2][k] * w2l[k * FC + j];
        h2s[(size_t)g2 * FC + j] = s * dis[g2];
    }
}

// ---------------- gather2 + self-loop + bias + log_softmax -> out ----------------

__global__ __launch_bounds__(256) void k_gather2(const int* __restrict__ off,
                                                 const int* __restrict__ esrc,
                                                 const float* __restrict__ h2s,
                                                 const float* __restrict__ dis,
                                                 const float* __restrict__ b2,
                                                 float* __restrict__ out) {
    int g = blockIdx.x * (256 / FC) + threadIdx.x / FC;
    int f = threadIdx.x & (FC - 1);
    int s0 = off[g], s1 = off[g + 1];
    float acc = 0.0f, acc2 = 0.0f;
    int i = s0;
    for (; i + 1 < s1; i += 2) {
        int r0 = esrc[i], r1 = esrc[i + 1];
        acc += h2s[(size_t)r0 * FC + f];
        acc2 += h2s[(size_t)r1 * FC + f];
    }
    if (i < s1) acc += h2s[(size_t)esrc[i] * FC + f];
    acc += acc2 + h2s[(size_t)g * FC + f];
    float v = dis[g] * acc + b2[f];
    float m = v;
#pragma unroll
    for (int o = 1; o < FC; o <<= 1) m = fmaxf(m, __shfl_xor(m, o, FC));
    float e = __expf(v - m);
    float s = e;
#pragma unroll
    for (int o = 1; o < FC; o <<= 1) s += __shfl_xor(s, o, FC);
    out[(size_t)g * FC + f] = v - m - logf(s);
}

extern "C" void kernel_launch(void* const* d_in, const int* in_sizes, int n_in,
                              void* d_out, int out_size, void* d_ws, size_t ws_size,
                              hipStream_t stream) {
    const float* x  = (const float*)d_in[0];
    const int*   ei = (const int*)d_in[1];
    const float* W1 = (const float*)d_in[2];
    const float* b1 = (const float*)d_in[3];
    const float* W2 = (const float*)d_in[4];
    const float* b2 = (const float*)d_in[5];
    float* out = (float*)d_out;

    const int* row = ei;
    const int* col = ei + NE;

    // workspace layout (int units, ~41.2 MB; every region 16B-aligned)
    int* base = (int*)d_ws;
    unsigned char* ghist = (unsigned char*)base;            // M_SL*NN u8 = 1.6M ints
    unsigned char* rank  = ghist + (size_t)M_SL * NN;       // NE u8 = 0.4M ints
    int*   cnt   = base + 1600000 + 400000;                 // NN
    int*   off   = cnt + NN;                                // NN+1 (pad 8)
    int*   part  = off + NN + 8;                            // 128
    float* dis   = (float*)(part + 128);                    // NN
    unsigned short* wbuf = (unsigned short*)(dis + NN);     // 16384 u16 = 8192 ints
    float* h1    = (float*)(wbuf + 16384);                  // NN*FH
    float* h1s   = h1 + (size_t)NN * FH;                    // NN*FH
    int*   esrc  = (int*)(h1s + (size_t)NN * FH);           // NE
    float* h2s   = h1;                                      // alias: h1 dead after scale

    const int B = 256;

    k_prep<<<1, B, 0, stream>>>(W1, wbuf);
    k_hist_gemm1<<<M_SL + NGB1, B, 0, stream>>>(col, ghist, rank, x, wbuf, h1);
    k_xscan<<<NBLK, SCAN_B, 0, stream>>>(ghist, cnt, dis, part);
    k_scanpart<<<1, 128, 0, stream>>>(part);
    k_scan_scale<<<NBLK + SCALE_B, SCAN_B, 0, stream>>>(cnt, part, off,
                                                        (const float4*)h1, (float4*)h1s, dis);
    k_fill<<<NCB, B, 0, stream>>>(row, col, rank, off, ghist, esrc);
    k_gather1g2<<<NN / 8, B, 0, stream>>>(off, esrc, h1s, dis, b1, W2, h2s);
    k_gather2<<<NN * FC / 256, B, 0, stream>>>(off, esrc, h2s, dis, b2, out);
}

// Round 11
// 220.341 us; speedup vs baseline: 1.2730x; 1.2730x over previous
//
#include <hip/hip_runtime.h>
#include <hip/hip_bf16.h>

#define NN 100000
#define NE 1600000
#define FIN 512
#define FH 32
#define FC 16
#define SCAN_B 1024
#define NBLK ((NN + SCAN_B - 1) / SCAN_B)   // 98
#define NCB ((NE / 4 + 255) / 256)          // 1563 fill blocks
#define M_SL 128                            // edge slices
#define SLICE (NE / M_SL)                   // 12500 edges/slice
#define QSL (SLICE / 4)                     // 3125 quads/slice
#define PSZ 32768                           // nodes per pass (byte-packed 32 KB LDS)
#define NP ((NN + PSZ - 1) / PSZ)           // 4 passes
#define NHB (M_SL * NP)                     // 512 hist blocks
#define NGB1 ((NN + 63) / 64)               // 1563 MFMA gemm blocks
#define SCALE_B ((NN * FH / 4 + SCAN_B - 1) / SCAN_B)  // 782

typedef __attribute__((ext_vector_type(8))) short bf16x8;
typedef __attribute__((ext_vector_type(4))) float f32x4;

__device__ inline unsigned short f2bf(float f) {
    unsigned u = __float_as_uint(f);
    return (unsigned short)((u + 0x7FFFu + ((u >> 16) & 1u)) >> 16);  // RNE
}

// ---------------- prep: W1 -> bf16, pre-swizzled to B-fragment order ----------------

__global__ __launch_bounds__(256) void k_prep(const float* __restrict__ W1,
                                              unsigned short* __restrict__ wbuf) {
    for (int idx = threadIdx.x; idx < 16 * 2 * 64; idx += 256) {
        int s = idx >> 7;
        int t = (idx >> 6) & 1;
        int l = idx & 63;
        int k0 = s * 32 + (l >> 4) * 8;
        int c = t * 16 + (l & 15);
        bf16x8 w;
#pragma unroll
        for (int i = 0; i < 8; ++i) w[i] = (short)f2bf(W1[(size_t)(k0 + i) * FH + c]);
        *(bf16x8*)(wbuf + (size_t)idx * 8) = w;
    }
}

// ---------------- fused: MFMA GEMM1  +  byte-packed LDS hist ----------------
// blocks [0, NGB1): bf16 MFMA GEMM h1 = x @ W1 (64 nodes/block).
// blocks [NGB1, NGB1+NHB): hist pass p = hb/M_SL, slice m = hb%M_SL;
//   4 node-counters packed per LDS word -> 32768 nodes per 32 KB pass.

__global__ __launch_bounds__(256) void k_hist_gemm1(const int* __restrict__ col,
                                                    unsigned char* __restrict__ ghist,
                                                    unsigned char* __restrict__ rank,
                                                    const float* __restrict__ x,
                                                    const unsigned short* __restrict__ wbuf,
                                                    float* __restrict__ h1) {
    __shared__ int sh[PSZ / 4];  // 32 KB; gemm path reuses as bf16 W store

    if (blockIdx.x >= NGB1) {
        int hb = blockIdx.x - NGB1;
        int p = hb / M_SL;
        int m = hb % M_SL;
        int base = p * PSZ;
        int nb = min(PSZ, NN - base);
        int nw = (nb + 3) >> 2;
        unsigned* shw = (unsigned*)sh;
        for (int i = threadIdx.x; i < nw; i += 256) shw[i] = 0u;
        __syncthreads();
        const int4* c4p = (const int4*)(col + m * SLICE);
        for (int it = 0; it < (QSL + 255) / 256; ++it) {
            int q = it * 256 + threadIdx.x;
            if (q < QSL) {
                int4 c4 = c4p[q];
                int e = m * SLICE + q * 4;
                int cc[4] = {c4.x, c4.y, c4.z, c4.w};
#pragma unroll
                for (int u = 0; u < 4; ++u) {
                    int d = cc[u] - base;
                    if ((unsigned)d < (unsigned)nb) {
                        int sft = 8 * (d & 3);
                        unsigned old = atomicAdd(&shw[d >> 2], 1u << sft);
                        rank[e + u] = (unsigned char)((old >> sft) & 0xFFu);
                    }
                }
            }
        }
        __syncthreads();
        unsigned* gdst = (unsigned*)(ghist + (size_t)m * NN + base);  // 4B-aligned
        for (int i = threadIdx.x; i < nw; i += 256) gdst[i] = shw[i];
        return;
    }

    // ---- MFMA GEMM1 ----
    unsigned short* lb = (unsigned short*)sh;
    for (int i = threadIdx.x; i < 2048; i += 256)
        ((int4*)lb)[i] = ((const int4*)wbuf)[i];  // coalesced 32 KB stage
    __syncthreads();

    int wave = threadIdx.x >> 6;
    int lane = threadIdx.x & 63;
    int rowbase = blockIdx.x * 64 + wave * 16;
    int arow = rowbase + (lane & 15);
    int arowc = min(arow, NN - 1);
    int kgrp = (lane >> 4) * 8;

    f32x4 acc0 = {0.f, 0.f, 0.f, 0.f};
    f32x4 acc1 = {0.f, 0.f, 0.f, 0.f};
    const float* xrow = x + (size_t)arowc * FIN + kgrp;

    for (int sg = 0; sg < 16; sg += 4) {
        float4 av[8];
#pragma unroll
        for (int u = 0; u < 4; ++u) {
            av[2 * u]     = *(const float4*)(xrow + (sg + u) * 32);
            av[2 * u + 1] = *(const float4*)(xrow + (sg + u) * 32 + 4);
        }
#pragma unroll
        for (int u = 0; u < 4; ++u) {
            const float* s0 = (const float*)&av[2 * u];
            const float* s1 = (const float*)&av[2 * u + 1];
            bf16x8 af;
            af[0] = (short)f2bf(s0[0]); af[1] = (short)f2bf(s0[1]);
            af[2] = (short)f2bf(s0[2]); af[3] = (short)f2bf(s0[3]);
            af[4] = (short)f2bf(s1[0]); af[5] = (short)f2bf(s1[1]);
            af[6] = (short)f2bf(s1[2]); af[7] = (short)f2bf(s1[3]);
            int s = sg + u;
            bf16x8 b0 = *(const bf16x8*)(lb + ((size_t)(s * 2 + 0) * 64 + lane) * 8);
            bf16x8 b1 = *(const bf16x8*)(lb + ((size_t)(s * 2 + 1) * 64 + lane) * 8);
            acc0 = __builtin_amdgcn_mfma_f32_16x16x32_bf16(af, b0, acc0, 0, 0, 0);
            acc1 = __builtin_amdgcn_mfma_f32_16x16x32_bf16(af, b1, acc1, 0, 0, 0);
        }
    }

    int crow = rowbase + (lane >> 4) * 4;
    int ccol = lane & 15;
#pragma unroll
    for (int r = 0; r < 4; ++r) {
        if (crow + r < NN) {
            h1[(size_t)(crow + r) * FH + ccol] = acc0[r];
            h1[(size_t)(crow + r) * FH + 16 + ccol] = acc1[r];
        }
    }
}

// ---------------- per-node slice-scan: ghist -> per-slice prefix; cnt, dis, part ----------------

__global__ __launch_bounds__(SCAN_B) void k_xscan(unsigned char* __restrict__ ghist,
                                                  int* __restrict__ cnt,
                                                  float* __restrict__ dis,
                                                  int* __restrict__ part) {
    __shared__ int s[SCAN_B];
    int c = blockIdx.x * SCAN_B + threadIdx.x;
    int sum = 0;
    if (c < NN) {
        for (int m = 0; m < M_SL; ++m) {
            size_t idx = (size_t)m * NN + c;
            int t = ghist[idx];
            ghist[idx] = (unsigned char)sum;  // exclusive per-slice prefix
            sum += t;
        }
        cnt[c] = sum;
        dis[c] = rsqrtf((float)sum + 1.0f);  // +1 self-loop
    }
    s[threadIdx.x] = sum;
    __syncthreads();
    for (int st = SCAN_B / 2; st > 0; st >>= 1) {
        if (threadIdx.x < st) s[threadIdx.x] += s[threadIdx.x + st];
        __syncthreads();
    }
    if (threadIdx.x == 0) part[blockIdx.x] = s[0];
}

// ---------------- scan of partials ----------------

__global__ __launch_bounds__(128) void k_scanpart(int* __restrict__ part) {
    __shared__ int s[128];
    int t = threadIdx.x;
    int v = (t < NBLK) ? part[t] : 0;
    s[t] = v;
    __syncthreads();
    for (int st = 1; st < 128; st <<= 1) {
        int a = (t >= st) ? s[t - st] : 0;
        __syncthreads();
        s[t] += a;
        __syncthreads();
    }
    if (t < NBLK) part[t] = s[t] - v;  // exclusive
}

// ---------------- fused: node-offset scan  +  h1s = h1 * dis[node] ----------------

__global__ __launch_bounds__(SCAN_B) void k_scan_scale(const int* __restrict__ cnt,
                                                       const int* __restrict__ part,
                                                       int* __restrict__ off,
                                                       const float4* __restrict__ h1,
                                                       float4* __restrict__ h1s,
                                                       const float* __restrict__ dis) {
    __shared__ int s[SCAN_B];
    int bid = blockIdx.x;
    if (bid < NBLK) {
        int i = bid * SCAN_B + threadIdx.x;
        int v = (i < NN) ? cnt[i] : 0;
        s[threadIdx.x] = v;
        __syncthreads();
        for (int st = 1; st < SCAN_B; st <<= 1) {
            int add = (threadIdx.x >= st) ? s[threadIdx.x - st] : 0;
            __syncthreads();
            s[threadIdx.x] += add;
            __syncthreads();
        }
        if (i < NN) off[i] = part[bid] + s[threadIdx.x] - v;  // exclusive
        if (i == NN - 1) off[NN] = part[bid] + s[threadIdx.x];
    } else {
        int i4 = (bid - NBLK) * SCAN_B + threadIdx.x;
        if (i4 < NN * FH / 4) {
            float4 v = h1[i4];
            float d = dis[i4 >> 3];
            h1s[i4] = make_float4(v.x * d, v.y * d, v.z * d, v.w * d);
        }
    }
}

// ---------------- CSR fill: atomic-free, slot = off[c] + ghist[m][c] + rank ----------------

__global__ void k_fill(const int* __restrict__ row, const int* __restrict__ col,
                       const unsigned char* __restrict__ rank,
                       const int* __restrict__ off,
                       const unsigned char* __restrict__ ghist,
                       int* __restrict__ esrc) {
    int i = blockIdx.x * blockDim.x + threadIdx.x;  // global quad index
    if (i >= NE / 4) return;
    int m = i / QSL;  // slice
    int4 r4 = ((const int4*)row)[i];
    int4 c4 = ((const int4*)col)[i];
    uchar4 rk4 = ((const uchar4*)rank)[i];
    int rr[4] = {r4.x, r4.y, r4.z, r4.w};
    int cc[4] = {c4.x, c4.y, c4.z, c4.w};
    int rk[4] = {rk4.x, rk4.y, rk4.z, rk4.w};
    int o4[4], bp[4];
#pragma unroll
    for (int u = 0; u < 4; ++u) o4[u] = off[cc[u]];
#pragma unroll
    for (int u = 0; u < 4; ++u) bp[u] = ghist[(size_t)m * NN + cc[u]];
#pragma unroll
    for (int u = 0; u < 4; ++u) esrc[o4[u] + bp[u] + rk[u]] = rr[u];
}

// ---------------- gather1 + relu + GEMM2 fused: h2s = relu(...)@W2 * dis ----------------
// 8 nodes/block, 32 lanes/node

__global__ __launch_bounds__(256) void k_gather1g2(const int* __restrict__ off,
                                                   const int* __restrict__ esrc,
                                                   const float* __restrict__ h1s,
                                                   const float* __restrict__ dis,
                                                   const float* __restrict__ b1,
                                                   const float* __restrict__ W2,
                                                   float* __restrict__ h2s) {
    __shared__ float w2l[FH * FC];     // 2 KB
    __shared__ float hrl[8][FH + 1];   // padded: no bank conflict in dot loop
    for (int i = threadIdx.x; i < FH * FC; i += 256) w2l[i] = W2[i];

    int ng = threadIdx.x >> 5;
    int f = threadIdx.x & 31;
    int g = blockIdx.x * 8 + ng;
    int s0 = off[g], s1 = off[g + 1];
    float acc = 0.0f, acc2 = 0.0f;
    int i = s0;
    for (; i + 1 < s1; i += 2) {
        int r0 = esrc[i], r1 = esrc[i + 1];
        acc += h1s[(size_t)r0 * FH + f];
        acc2 += h1s[(size_t)r1 * FH + f];
    }
    if (i < s1) acc += h1s[(size_t)esrc[i] * FH + f];
    acc += acc2 + h1s[(size_t)g * FH + f];
    float v = dis[g] * acc + b1[f];
    hrl[ng][f] = v > 0.0f ? v : 0.0f;
    __syncthreads();

    if (threadIdx.x < 128) {
        int ng2 = threadIdx.x >> 4;
        int j = threadIdx.x & 15;
        int g2 = blockIdx.x * 8 + ng2;
        float s = 0.0f;
#pragma unroll
        for (int k = 0; k < FH; ++k) s += hrl[ng2][k] * w2l[k * FC + j];
        h2s[(size_t)g2 * FC + j] = s * dis[g2];
    }
}

// ---------------- gather2 + self-loop + bias + log_softmax -> out ----------------

__global__ __launch_bounds__(256) void k_gather2(const int* __restrict__ off,
                                                 const int* __restrict__ esrc,
                                                 const float* __restrict__ h2s,
                                                 const float* __restrict__ dis,
                                                 const float* __restrict__ b2,
                                                 float* __restrict__ out) {
    int g = blockIdx.x * (256 / FC) + threadIdx.x / FC;
    int f = threadIdx.x & (FC - 1);
    int s0 = off[g], s1 = off[g + 1];
    float acc = 0.0f, acc2 = 0.0f;
    int i = s0;
    for (; i + 1 < s1; i += 2) {
        int r0 = esrc[i], r1 = esrc[i + 1];
        acc += h2s[(size_t)r0 * FC + f];
        acc2 += h2s[(size_t)r1 * FC + f];
    }
    if (i < s1) acc += h2s[(size_t)esrc[i] * FC + f];
    acc += acc2 + h2s[(size_t)g * FC + f];
    float v = dis[g] * acc + b2[f];
    float m = v;
#pragma unroll
    for (int o = 1; o < FC; o <<= 1) m = fmaxf(m, __shfl_xor(m, o, FC));
    float e = __expf(v - m);
    float s = e;
#pragma unroll
    for (int o = 1; o < FC; o <<= 1) s += __shfl_xor(s, o, FC);
    out[(size_t)g * FC + f] = v - m - logf(s);
}

extern "C" void kernel_launch(void* const* d_in, const int* in_sizes, int n_in,
                              void* d_out, int out_size, void* d_ws, size_t ws_size,
                              hipStream_t stream) {
    const float* x  = (const float*)d_in[0];
    const int*   ei = (const int*)d_in[1];
    const float* W1 = (const float*)d_in[2];
    const float* b1 = (const float*)d_in[3];
    const float* W2 = (const float*)d_in[4];
    const float* b2 = (const float*)d_in[5];
    float* out = (float*)d_out;

    const int* row = ei;
    const int* col = ei + NE;

    // workspace layout (int units, ~48 MB; every region 16B-aligned)
    int* base = (int*)d_ws;
    unsigned char* ghist = (unsigned char*)base;            // M_SL*NN u8 = 12.8 MB (3.2M ints)
    unsigned char* rank  = ghist + (size_t)M_SL * NN;       // NE u8 = 0.4M ints
    int*   cnt   = base + 3200000 + 400000;                 // NN
    int*   off   = cnt + NN;                                // NN+1 (pad 8)
    int*   part  = off + NN + 8;                            // 128
    float* dis   = (float*)(part + 128);                    // NN
    unsigned short* wbuf = (unsigned short*)(dis + NN);     // 16384 u16 = 8192 ints
    float* h1    = (float*)(wbuf + 16384);                  // NN*FH
    float* h1s   = h1 + (size_t)NN * FH;                    // NN*FH
    int*   esrc  = (int*)(h1s + (size_t)NN * FH);           // NE
    float* h2s   = h1;                                      // alias: h1 dead after scale

    const int B = 256;

    k_prep<<<1, B, 0, stream>>>(W1, wbuf);
    k_hist_gemm1<<<NGB1 + NHB, B, 0, stream>>>(col, ghist, rank, x, wbuf, h1);
    k_xscan<<<NBLK, SCAN_B, 0, stream>>>(ghist, cnt, dis, part);
    k_scanpart<<<1, 128, 0, stream>>>(part);
    k_scan_scale<<<NBLK + SCALE_B, SCAN_B, 0, stream>>>(cnt, part, off,
                                                        (const float4*)h1, (float4*)h1s, dis);
    k_fill<<<NCB, B, 0, stream>>>(row, col, rank, off, ghist, esrc);
    k_gather1g2<<<NN / 8, B, 0, stream>>>(off, esrc, h1s, dis, b1, W2, h2s);
    k_gather2<<<NN * FC / 256, B, 0, stream>>>(off, esrc, h2s, dis, b2, out);
}

// Round 12
// 196.684 us; speedup vs baseline: 1.4262x; 1.1203x over previous
//
#include <hip/hip_runtime.h>
#include <hip/hip_bf16.h>

#define NN 100000
#define NE 1600000
#define FIN 512
#define FH 32
#define FC 16
#define NCB ((NE / 4 + 255) / 256)          // 1563 fill blocks
#define M_SL 128                            // edge slices
#define SLICE (NE / M_SL)                   // 12500 edges/slice
#define QSL (SLICE / 4)                     // 3125 quads/slice
#define PSZ 32768                           // nodes per pass (byte-packed 32 KB LDS)
#define NP ((NN + PSZ - 1) / PSZ)           // 4 passes
#define NHB (M_SL * NP)                     // 512 hist blocks
#define NGB1 ((NN + 63) / 64)               // 1563 MFMA gemm blocks
#define XW (NN / 4)                         // 25000 ghist words per slice
#define XSB ((XW + 255) / 256)              // 98 xscan blocks
#define SOS_NB 98                           // off-scan blocks (1024 nodes each)
#define SCALE_B ((NN * FH / 4 + 1023) / 1024)  // 782 scale blocks

typedef __attribute__((ext_vector_type(8))) short bf16x8;
typedef __attribute__((ext_vector_type(4))) float f32x4;

__device__ inline unsigned short f2bf(float f) {
    unsigned u = __float_as_uint(f);
    return (unsigned short)((u + 0x7FFFu + ((u >> 16) & 1u)) >> 16);  // RNE
}
__device__ inline float bf2f(unsigned short u) {
    return __uint_as_float(((unsigned)u) << 16);
}

// ---------------- prep: W1 -> bf16, pre-swizzled to B-fragment order ----------------

__global__ __launch_bounds__(256) void k_prep(const float* __restrict__ W1,
                                              unsigned short* __restrict__ wbuf) {
    for (int idx = threadIdx.x; idx < 16 * 2 * 64; idx += 256) {
        int s = idx >> 7;
        int t = (idx >> 6) & 1;
        int l = idx & 63;
        int k0 = s * 32 + (l >> 4) * 8;
        int c = t * 16 + (l & 15);
        bf16x8 w;
#pragma unroll
        for (int i = 0; i < 8; ++i) w[i] = (short)f2bf(W1[(size_t)(k0 + i) * FH + c]);
        *(bf16x8*)(wbuf + (size_t)idx * 8) = w;
    }
}

// ---------------- fused: MFMA GEMM1  +  byte-packed LDS hist ----------------

__global__ __launch_bounds__(256) void k_hist_gemm1(const int* __restrict__ col,
                                                    unsigned char* __restrict__ ghist,
                                                    unsigned char* __restrict__ rank,
                                                    const float* __restrict__ x,
                                                    const unsigned short* __restrict__ wbuf,
                                                    float* __restrict__ h1) {
    __shared__ int sh[PSZ / 4];  // 32 KB; gemm path reuses as bf16 W store

    if (blockIdx.x >= NGB1) {
        int hb = blockIdx.x - NGB1;
        int p = hb / M_SL;
        int m = hb % M_SL;
        int base = p * PSZ;
        int nb = min(PSZ, NN - base);
        int nw = (nb + 3) >> 2;
        unsigned* shw = (unsigned*)sh;
        for (int i = threadIdx.x; i < nw; i += 256) shw[i] = 0u;
        __syncthreads();
        const int4* c4p = (const int4*)(col + m * SLICE);
        for (int it = 0; it < (QSL + 255) / 256; ++it) {
            int q = it * 256 + threadIdx.x;
            if (q < QSL) {
                int4 c4 = c4p[q];
                int e = m * SLICE + q * 4;
                int cc[4] = {c4.x, c4.y, c4.z, c4.w};
#pragma unroll
                for (int u = 0; u < 4; ++u) {
                    int d = cc[u] - base;
                    if ((unsigned)d < (unsigned)nb) {
                        int sft = 8 * (d & 3);
                        unsigned old = atomicAdd(&shw[d >> 2], 1u << sft);
                        rank[e + u] = (unsigned char)((old >> sft) & 0xFFu);
                    }
                }
            }
        }
        __syncthreads();
        unsigned* gdst = (unsigned*)(ghist + (size_t)m * NN + base);  // 4B-aligned
        for (int i = threadIdx.x; i < nw; i += 256) gdst[i] = shw[i];
        return;
    }

    // ---- MFMA GEMM1 ----
    unsigned short* lb = (unsigned short*)sh;
    for (int i = threadIdx.x; i < 2048; i += 256)
        ((int4*)lb)[i] = ((const int4*)wbuf)[i];  // coalesced 32 KB stage
    __syncthreads();

    int wave = threadIdx.x >> 6;
    int lane = threadIdx.x & 63;
    int rowbase = blockIdx.x * 64 + wave * 16;
    int arow = rowbase + (lane & 15);
    int arowc = min(arow, NN - 1);
    int kgrp = (lane >> 4) * 8;

    f32x4 acc0 = {0.f, 0.f, 0.f, 0.f};
    f32x4 acc1 = {0.f, 0.f, 0.f, 0.f};
    const float* xrow = x + (size_t)arowc * FIN + kgrp;

    for (int sg = 0; sg < 16; sg += 4) {
        float4 av[8];
#pragma unroll
        for (int u = 0; u < 4; ++u) {
            av[2 * u]     = *(const float4*)(xrow + (sg + u) * 32);
            av[2 * u + 1] = *(const float4*)(xrow + (sg + u) * 32 + 4);
        }
#pragma unroll
        for (int u = 0; u < 4; ++u) {
            const float* s0 = (const float*)&av[2 * u];
            const float* s1 = (const float*)&av[2 * u + 1];
            bf16x8 af;
            af[0] = (short)f2bf(s0[0]); af[1] = (short)f2bf(s0[1]);
            af[2] = (short)f2bf(s0[2]); af[3] = (short)f2bf(s0[3]);
            af[4] = (short)f2bf(s1[0]); af[5] = (short)f2bf(s1[1]);
            af[6] = (short)f2bf(s1[2]); af[7] = (short)f2bf(s1[3]);
            int s = sg + u;
            bf16x8 b0 = *(const bf16x8*)(lb + ((size_t)(s * 2 + 0) * 64 + lane) * 8);
            bf16x8 b1 = *(const bf16x8*)(lb + ((size_t)(s * 2 + 1) * 64 + lane) * 8);
            acc0 = __builtin_amdgcn_mfma_f32_16x16x32_bf16(af, b0, acc0, 0, 0, 0);
            acc1 = __builtin_amdgcn_mfma_f32_16x16x32_bf16(af, b1, acc1, 0, 0, 0);
        }
    }

    int crow = rowbase + (lane >> 4) * 4;
    int ccol = lane & 15;
#pragma unroll
    for (int r = 0; r < 4; ++r) {
        if (crow + r < NN) {
            h1[(size_t)(crow + r) * FH + ccol] = acc0[r];
            h1[(size_t)(crow + r) * FH + 16 + ccol] = acc1[r];
        }
    }
}

// ---------------- SWAR slice-scan: 4 nodes/thread via u32 words ----------------
// ghist[m][c] -> exclusive per-slice prefix (bytes); cnt, dis, per-block sums -> part

__global__ __launch_bounds__(256) void k_xscan(unsigned* __restrict__ ghistw,
                                               int* __restrict__ cnt,
                                               float* __restrict__ dis,
                                               int* __restrict__ part) {
    __shared__ int red[256];
    int widx = blockIdx.x * 256 + threadIdx.x;
    int tot = 0;
    if (widx < XW) {
        unsigned s0 = 0, s1 = 0, s2 = 0, s3 = 0;
        unsigned* p = ghistw + widx;
        for (int m = 0; m < M_SL; ++m) {
            unsigned w = p[(size_t)m * XW];
            p[(size_t)m * XW] = s0 | (s1 << 8) | (s2 << 16) | (s3 << 24);
            s0 += w & 0xFFu; s1 += (w >> 8) & 0xFFu;
            s2 += (w >> 16) & 0xFFu; s3 += (w >> 24) & 0xFFu;
        }
        int c0 = widx * 4;
        *(int4*)(cnt + c0) = make_int4(s0, s1, s2, s3);
        *(float4*)(dis + c0) = make_float4(rsqrtf((float)s0 + 1.f), rsqrtf((float)s1 + 1.f),
                                           rsqrtf((float)s2 + 1.f), rsqrtf((float)s3 + 1.f));
        tot = s0 + s1 + s2 + s3;
    }
    red[threadIdx.x] = tot;
    __syncthreads();
    for (int st = 128; st > 0; st >>= 1) {
        if (threadIdx.x < st) red[threadIdx.x] += red[threadIdx.x + st];
        __syncthreads();
    }
    if (threadIdx.x == 0) part[blockIdx.x] = red[0];
}

// ---------------- fused: off-scan (with inline part-scan)  +  h1s = bf16(h1 * dis) ----------------

__global__ __launch_bounds__(1024) void k_scan_off_scale(const int* __restrict__ cnt,
                                                         const int* __restrict__ part,
                                                         int* __restrict__ off,
                                                         const float4* __restrict__ h1,
                                                         ushort4* __restrict__ h1s,
                                                         const float* __restrict__ dis) {
    int bid = blockIdx.x;
    if (bid < SOS_NB) {
        __shared__ int s[1024];
        __shared__ int sp[128];
        if (threadIdx.x < 128) sp[threadIdx.x] = (threadIdx.x < XSB) ? part[threadIdx.x] : 0;
        __syncthreads();
        for (int st = 1; st < 128; st <<= 1) {
            int a = (threadIdx.x < 128 && threadIdx.x >= st) ? sp[threadIdx.x - st] : 0;
            __syncthreads();
            if (threadIdx.x < 128) sp[threadIdx.x] += a;
            __syncthreads();
        }
        int pbase = (bid == 0) ? 0 : sp[bid - 1];
        int i = bid * 1024 + threadIdx.x;
        int v = (i < NN) ? cnt[i] : 0;
        s[threadIdx.x] = v;
        __syncthreads();
        for (int st = 1; st < 1024; st <<= 1) {
            int a = (threadIdx.x >= st) ? s[threadIdx.x - st] : 0;
            __syncthreads();
            s[threadIdx.x] += a;
            __syncthreads();
        }
        if (i < NN) off[i] = pbase + s[threadIdx.x] - v;  // exclusive
        if (i == NN - 1) off[NN] = pbase + s[threadIdx.x];
    } else {
        int idx = (bid - SOS_NB) * 1024 + threadIdx.x;
        if (idx < NN * FH / 4) {
            float4 v = h1[idx];
            float d = dis[idx >> 3];
            ushort4 o;
            o.x = f2bf(v.x * d); o.y = f2bf(v.y * d);
            o.z = f2bf(v.z * d); o.w = f2bf(v.w * d);
            h1s[idx] = o;
        }
    }
}

// ---------------- CSR fill: atomic-free, slot = off[c] + ghist[m][c] + rank ----------------

__global__ void k_fill(const int* __restrict__ row, const int* __restrict__ col,
                       const unsigned char* __restrict__ rank,
                       const int* __restrict__ off,
                       const unsigned char* __restrict__ ghist,
                       int* __restrict__ esrc) {
    int i = blockIdx.x * blockDim.x + threadIdx.x;  // global quad index
    if (i >= NE / 4) return;
    int m = i / QSL;  // slice
    int4 r4 = ((const int4*)row)[i];
    int4 c4 = ((const int4*)col)[i];
    uchar4 rk4 = ((const uchar4*)rank)[i];
    int rr[4] = {r4.x, r4.y, r4.z, r4.w};
    int cc[4] = {c4.x, c4.y, c4.z, c4.w};
    int rk[4] = {rk4.x, rk4.y, rk4.z, rk4.w};
    int o4[4], bp[4];
#pragma unroll
    for (int u = 0; u < 4; ++u) o4[u] = off[cc[u]];
#pragma unroll
    for (int u = 0; u < 4; ++u) bp[u] = ghist[(size_t)m * NN + cc[u]];
#pragma unroll
    for (int u = 0; u < 4; ++u) esrc[o4[u] + bp[u] + rk[u]] = rr[u];
}

// ---------------- gather1 (bf16 rows) + relu + GEMM2: h2s = relu(...)@W2 * dis ----------------
// 8 nodes/block, 32 lanes/node

__global__ __launch_bounds__(256) void k_gather1g2(const int* __restrict__ off,
                                                   const int* __restrict__ esrc,
                                                   const unsigned short* __restrict__ h1s,
                                                   const float* __restrict__ dis,
                                                   const float* __restrict__ b1,
                                                   const float* __restrict__ W2,
                                                   float* __restrict__ h2s) {
    __shared__ float w2l[FH * FC];     // 2 KB
    __shared__ float hrl[8][FH + 1];   // padded
    for (int i = threadIdx.x; i < FH * FC; i += 256) w2l[i] = W2[i];

    int ng = threadIdx.x >> 5;
    int f = threadIdx.x & 31;
    int g = blockIdx.x * 8 + ng;
    int s0 = off[g], s1 = off[g + 1];
    float a0 = 0.f, a1 = 0.f, a2 = 0.f, a3 = 0.f;
    int i = s0;
    for (; i + 3 < s1; i += 4) {
        int r0 = esrc[i], r1 = esrc[i + 1], r2 = esrc[i + 2], r3 = esrc[i + 3];
        a0 += bf2f(h1s[(size_t)r0 * FH + f]);
        a1 += bf2f(h1s[(size_t)r1 * FH + f]);
        a2 += bf2f(h1s[(size_t)r2 * FH + f]);
        a3 += bf2f(h1s[(size_t)r3 * FH + f]);
    }
    for (; i < s1; ++i) a0 += bf2f(h1s[(size_t)esrc[i] * FH + f]);
    float acc = a0 + a1 + a2 + a3 + bf2f(h1s[(size_t)g * FH + f]);
    float v = dis[g] * acc + b1[f];
    hrl[ng][f] = v > 0.0f ? v : 0.0f;
    __syncthreads();

    if (threadIdx.x < 128) {
        int ng2 = threadIdx.x >> 4;
        int j = threadIdx.x & 15;
        int g2 = blockIdx.x * 8 + ng2;
        float s = 0.0f;
#pragma unroll
        for (int k = 0; k < FH; ++k) s += hrl[ng2][k] * w2l[k * FC + j];
        h2s[(size_t)g2 * FC + j] = s * dis[g2];
    }
}

// ---------------- gather2 + self-loop + bias + log_softmax -> out ----------------

__global__ __launch_bounds__(256) void k_gather2(const int* __restrict__ off,
                                                 const int* __restrict__ esrc,
                                                 const float* __restrict__ h2s,
                                                 const float* __restrict__ dis,
                                                 const float* __restrict__ b2,
                                                 float* __restrict__ out) {
    int g = blockIdx.x * (256 / FC) + threadIdx.x / FC;
    int f = threadIdx.x & (FC - 1);
    int s0 = off[g], s1 = off[g + 1];
    float a0 = 0.f, a1 = 0.f, a2 = 0.f, a3 = 0.f;
    int i = s0;
    for (; i + 3 < s1; i += 4) {
        int r0 = esrc[i], r1 = esrc[i + 1], r2 = esrc[i + 2], r3 = esrc[i + 3];
        a0 += h2s[(size_t)r0 * FC + f];
        a1 += h2s[(size_t)r1 * FC + f];
        a2 += h2s[(size_t)r2 * FC + f];
        a3 += h2s[(size_t)r3 * FC + f];
    }
    for (; i < s1; ++i) a0 += h2s[(size_t)esrc[i] * FC + f];
    float acc = a0 + a1 + a2 + a3 + h2s[(size_t)g * FC + f];
    float v = dis[g] * acc + b2[f];
    float m = v;
#pragma unroll
    for (int o = 1; o < FC; o <<= 1) m = fmaxf(m, __shfl_xor(m, o, FC));
    float e = __expf(v - m);
    float s = e;
#pragma unroll
    for (int o = 1; o < FC; o <<= 1) s += __shfl_xor(s, o, FC);
    out[(size_t)g * FC + f] = v - m - logf(s);
}

extern "C" void kernel_launch(void* const* d_in, const int* in_sizes, int n_in,
                              void* d_out, int out_size, void* d_ws, size_t ws_size,
                              hipStream_t stream) {
    const float* x  = (const float*)d_in[0];
    const int*   ei = (const int*)d_in[1];
    const float* W1 = (const float*)d_in[2];
    const float* b1 = (const float*)d_in[3];
    const float* W2 = (const float*)d_in[4];
    const float* b2 = (const float*)d_in[5];
    float* out = (float*)d_out;

    const int* row = ei;
    const int* col = ei + NE;

    // workspace layout (int units, ~38 MB; all regions 16B-aligned)
    int* base = (int*)d_ws;
    unsigned char* ghist = (unsigned char*)base;            // M_SL*NN u8 = 3.2M ints
    unsigned char* rank  = ghist + (size_t)M_SL * NN;       // NE u8 = 0.4M ints
    int*   cnt   = base + 3200000 + 400000;                 // NN
    int*   off   = cnt + NN;                                // NN+1 (pad 8)
    int*   part  = off + NN + 8;                            // 128
    float* dis   = (float*)(part + 128);                    // NN
    unsigned short* wbuf = (unsigned short*)(dis + NN);     // 16384 u16 = 8192 ints
    float* h1    = (float*)(wbuf + 16384);                  // NN*FH f32 (3.2M ints)
    unsigned short* h1s = (unsigned short*)(h1 + (size_t)NN * FH);  // NN*FH bf16 (1.6M ints)
    int*   esrc  = (int*)(h1s + (size_t)NN * FH);           // NE
    float* h2s   = h1;                                      // alias: h1 dead after scale

    const int B = 256;

    k_prep<<<1, B, 0, stream>>>(W1, wbuf);
    k_hist_gemm1<<<NGB1 + NHB, B, 0, stream>>>(col, ghist, rank, x, wbuf, h1);
    k_xscan<<<XSB, B, 0, stream>>>((unsigned*)ghist, cnt, dis, part);
    k_scan_off_scale<<<SOS_NB + SCALE_B, 1024, 0, stream>>>(cnt, part, off,
                                                            (const float4*)h1, (ushort4*)h1s, dis);
    k_fill<<<NCB, B, 0, stream>>>(row, col, rank, off, ghist, esrc);
    k_gather1g2<<<NN / 8, B, 0, stream>>>(off, esrc, h1s, dis, b1, W2, h2s);
    k_gather2<<<NN * FC / 256, B, 0, stream>>>(off, esrc, h2s, dis, b2, out);
}

// Round 13
// 186.187 us; speedup vs baseline: 1.5066x; 1.0564x over previous
//
#include <hip/hip_runtime.h>
#include <hip/hip_bf16.h>

#define NN 100000
#define NE 1600000
#define FIN 512
#define FH 32
#define FC 16
#define NCB ((NE / 4 + 255) / 256)          // 1563 fill blocks
#define M_SL 128                            // edge slices
#define SLICE (NE / M_SL)                   // 12500 edges/slice
#define QSL (SLICE / 4)                     // 3125 quads/slice
#define PSZ 32768                           // nodes per pass (byte-packed 32 KB LDS)
#define NP ((NN + PSZ - 1) / PSZ)           // 4 passes
#define NHB (M_SL * NP)                     // 512 hist blocks
#define NGB1 ((NN + 63) / 64)               // 1563 MFMA gemm blocks
#define XW (NN / 4)                         // 25000 ghist words per slice
#define XSB ((XW + 255) / 256)              // 98 xscan blocks
#define SOS_NB 98                           // off-scan blocks (1024 nodes each)
#define SCALE_B ((NN * FH / 4 + 1023) / 1024)  // 782 scale blocks

typedef __attribute__((ext_vector_type(8))) short bf16x8;
typedef __attribute__((ext_vector_type(4))) float f32x4;

__device__ inline unsigned short f2bf(float f) {
    unsigned u = __float_as_uint(f);
    return (unsigned short)((u + 0x7FFFu + ((u >> 16) & 1u)) >> 16);  // RNE
}
__device__ inline float bf2f(unsigned short u) {
    return __uint_as_float(((unsigned)u) << 16);
}
__device__ inline unsigned pk2bf(float a, float b) {  // packed 2xbf16 via v_cvt_pk_bf16_f32
    __hip_bfloat162 p = __float22bfloat162_rn(make_float2(a, b));
    union { __hip_bfloat162 h; unsigned u; } c;
    c.h = p;
    return c.u;
}

// ---------------- prep: W1 -> bf16, pre-swizzled to B-fragment order ----------------

__global__ __launch_bounds__(256) void k_prep(const float* __restrict__ W1,
                                              unsigned short* __restrict__ wbuf) {
    for (int idx = threadIdx.x; idx < 16 * 2 * 64; idx += 256) {
        int s = idx >> 7;
        int t = (idx >> 6) & 1;
        int l = idx & 63;
        int k0 = s * 32 + (l >> 4) * 8;
        int c = t * 16 + (l & 15);
        bf16x8 w;
#pragma unroll
        for (int i = 0; i < 8; ++i) w[i] = (short)f2bf(W1[(size_t)(k0 + i) * FH + c]);
        *(bf16x8*)(wbuf + (size_t)idx * 8) = w;
    }
}

// ---------------- fused: MFMA GEMM1 (cvt_pk A-build)  +  byte-packed LDS hist ----------------

__global__ __launch_bounds__(256) void k_hist_gemm1(const int* __restrict__ col,
                                                    unsigned char* __restrict__ ghist,
                                                    unsigned char* __restrict__ rank,
                                                    const float* __restrict__ x,
                                                    const unsigned short* __restrict__ wbuf,
                                                    float* __restrict__ h1) {
    __shared__ int sh[PSZ / 4];  // 32 KB; gemm path reuses as bf16 W store

    if (blockIdx.x >= NGB1) {
        int hb = blockIdx.x - NGB1;
        int p = hb / M_SL;
        int m = hb % M_SL;
        int base = p * PSZ;
        int nb = min(PSZ, NN - base);
        int nw = (nb + 3) >> 2;
        unsigned* shw = (unsigned*)sh;
        for (int i = threadIdx.x; i < nw; i += 256) shw[i] = 0u;
        __syncthreads();
        const int4* c4p = (const int4*)(col + m * SLICE);
        for (int it = 0; it < (QSL + 255) / 256; ++it) {
            int q = it * 256 + threadIdx.x;
            if (q < QSL) {
                int4 c4 = c4p[q];
                int e = m * SLICE + q * 4;
                int cc[4] = {c4.x, c4.y, c4.z, c4.w};
#pragma unroll
                for (int u = 0; u < 4; ++u) {
                    int d = cc[u] - base;
                    if ((unsigned)d < (unsigned)nb) {
                        int sft = 8 * (d & 3);
                        unsigned old = atomicAdd(&shw[d >> 2], 1u << sft);
                        rank[e + u] = (unsigned char)((old >> sft) & 0xFFu);
                    }
                }
            }
        }
        __syncthreads();
        unsigned* gdst = (unsigned*)(ghist + (size_t)m * NN + base);  // 4B-aligned
        for (int i = threadIdx.x; i < nw; i += 256) gdst[i] = shw[i];
        return;
    }

    // ---- MFMA GEMM1 ----
    unsigned short* lb = (unsigned short*)sh;
    for (int i = threadIdx.x; i < 2048; i += 256)
        ((int4*)lb)[i] = ((const int4*)wbuf)[i];  // coalesced 32 KB stage
    __syncthreads();

    int wave = threadIdx.x >> 6;
    int lane = threadIdx.x & 63;
    int rowbase = blockIdx.x * 64 + wave * 16;
    int arow = rowbase + (lane & 15);
    int arowc = min(arow, NN - 1);
    int kgrp = (lane >> 4) * 8;

    f32x4 acc0 = {0.f, 0.f, 0.f, 0.f};
    f32x4 acc1 = {0.f, 0.f, 0.f, 0.f};
    const float* xrow = x + (size_t)arowc * FIN + kgrp;

    for (int sg = 0; sg < 16; sg += 4) {
        float4 av[8];
#pragma unroll
        for (int u = 0; u < 4; ++u) {
            av[2 * u]     = *(const float4*)(xrow + (sg + u) * 32);
            av[2 * u + 1] = *(const float4*)(xrow + (sg + u) * 32 + 4);
        }
#pragma unroll
        for (int u = 0; u < 4; ++u) {
            const float* s0 = (const float*)&av[2 * u];
            const float* s1 = (const float*)&av[2 * u + 1];
            union { bf16x8 v; unsigned w[4]; } af;
            af.w[0] = pk2bf(s0[0], s0[1]);
            af.w[1] = pk2bf(s0[2], s0[3]);
            af.w[2] = pk2bf(s1[0], s1[1]);
            af.w[3] = pk2bf(s1[2], s1[3]);
            int s = sg + u;
            bf16x8 b0 = *(const bf16x8*)(lb + ((size_t)(s * 2 + 0) * 64 + lane) * 8);
            bf16x8 b1 = *(const bf16x8*)(lb + ((size_t)(s * 2 + 1) * 64 + lane) * 8);
            acc0 = __builtin_amdgcn_mfma_f32_16x16x32_bf16(af.v, b0, acc0, 0, 0, 0);
            acc1 = __builtin_amdgcn_mfma_f32_16x16x32_bf16(af.v, b1, acc1, 0, 0, 0);
        }
    }

    int crow = rowbase + (lane >> 4) * 4;
    int ccol = lane & 15;
#pragma unroll
    for (int r = 0; r < 4; ++r) {
        if (crow + r < NN) {
            h1[(size_t)(crow + r) * FH + ccol] = acc0[r];
            h1[(size_t)(crow + r) * FH + 16 + ccol] = acc1[r];
        }
    }
}

// ---------------- SWAR slice-scan: 4 nodes/thread via u32 words ----------------

__global__ __launch_bounds__(256) void k_xscan(unsigned* __restrict__ ghistw,
                                               int* __restrict__ cnt,
                                               float* __restrict__ dis,
                                               int* __restrict__ part) {
    __shared__ int red[256];
    int widx = blockIdx.x * 256 + threadIdx.x;
    int tot = 0;
    if (widx < XW) {
        unsigned s0 = 0, s1 = 0, s2 = 0, s3 = 0;
        unsigned* p = ghistw + widx;
        for (int m = 0; m < M_SL; ++m) {
            unsigned w = p[(size_t)m * XW];
            p[(size_t)m * XW] = s0 | (s1 << 8) | (s2 << 16) | (s3 << 24);
            s0 += w & 0xFFu; s1 += (w >> 8) & 0xFFu;
            s2 += (w >> 16) & 0xFFu; s3 += (w >> 24) & 0xFFu;
        }
        int c0 = widx * 4;
        *(int4*)(cnt + c0) = make_int4(s0, s1, s2, s3);
        *(float4*)(dis + c0) = make_float4(rsqrtf((float)s0 + 1.f), rsqrtf((float)s1 + 1.f),
                                           rsqrtf((float)s2 + 1.f), rsqrtf((float)s3 + 1.f));
        tot = s0 + s1 + s2 + s3;
    }
    red[threadIdx.x] = tot;
    __syncthreads();
    for (int st = 128; st > 0; st >>= 1) {
        if (threadIdx.x < st) red[threadIdx.x] += red[threadIdx.x + st];
        __syncthreads();
    }
    if (threadIdx.x == 0) part[blockIdx.x] = red[0];
}

// ---------------- fused: off-scan (inline part-scan)  +  h1s = bf16(h1 * dis) ----------------

__global__ __launch_bounds__(1024) void k_scan_off_scale(const int* __restrict__ cnt,
                                                         const int* __restrict__ part,
                                                         int* __restrict__ off,
                                                         const float4* __restrict__ h1,
                                                         ushort4* __restrict__ h1s,
                                                         const float* __restrict__ dis) {
    int bid = blockIdx.x;
    if (bid < SOS_NB) {
        __shared__ int s[1024];
        __shared__ int sp[128];
        if (threadIdx.x < 128) sp[threadIdx.x] = (threadIdx.x < XSB) ? part[threadIdx.x] : 0;
        __syncthreads();
        for (int st = 1; st < 128; st <<= 1) {
            int a = (threadIdx.x < 128 && threadIdx.x >= st) ? sp[threadIdx.x - st] : 0;
            __syncthreads();
            if (threadIdx.x < 128) sp[threadIdx.x] += a;
            __syncthreads();
        }
        int pbase = (bid == 0) ? 0 : sp[bid - 1];
        int i = bid * 1024 + threadIdx.x;
        int v = (i < NN) ? cnt[i] : 0;
        s[threadIdx.x] = v;
        __syncthreads();
        for (int st = 1; st < 1024; st <<= 1) {
            int a = (threadIdx.x >= st) ? s[threadIdx.x - st] : 0;
            __syncthreads();
            s[threadIdx.x] += a;
            __syncthreads();
        }
        if (i < NN) off[i] = pbase + s[threadIdx.x] - v;  // exclusive
        if (i == NN - 1) off[NN] = pbase + s[threadIdx.x];
    } else {
        int idx = (bid - SOS_NB) * 1024 + threadIdx.x;
        if (idx < NN * FH / 4) {
            float4 v = h1[idx];
            float d = dis[idx >> 3];
            union { ushort4 s4; unsigned u[2]; } o;
            o.u[0] = pk2bf(v.x * d, v.y * d);
            o.u[1] = pk2bf(v.z * d, v.w * d);
            h1s[idx] = o.s4;
        }
    }
}

// ---------------- CSR fill: atomic-free, slot = off[c] + ghist[m][c] + rank ----------------

__global__ void k_fill(const int* __restrict__ row, const int* __restrict__ col,
                       const unsigned char* __restrict__ rank,
                       const int* __restrict__ off,
                       const unsigned char* __restrict__ ghist,
                       int* __restrict__ esrc) {
    int i = blockIdx.x * blockDim.x + threadIdx.x;  // global quad index
    if (i >= NE / 4) return;
    int m = i / QSL;  // slice
    int4 r4 = ((const int4*)row)[i];
    int4 c4 = ((const int4*)col)[i];
    uchar4 rk4 = ((const uchar4*)rank)[i];
    int rr[4] = {r4.x, r4.y, r4.z, r4.w};
    int cc[4] = {c4.x, c4.y, c4.z, c4.w};
    int rk[4] = {rk4.x, rk4.y, rk4.z, rk4.w};
    int o4[4], bp[4];
#pragma unroll
    for (int u = 0; u < 4; ++u) o4[u] = off[cc[u]];
#pragma unroll
    for (int u = 0; u < 4; ++u) bp[u] = ghist[(size_t)m * NN + cc[u]];
#pragma unroll
    for (int u = 0; u < 4; ++u) esrc[o4[u] + bp[u] + rk[u]] = rr[u];
}

// ---------------- gather1 (ushort2 lanes) + relu + GEMM2: h2s = relu(...)@W2 * dis ----------------
// 16 nodes/block, 16 lanes/node, 2 features/lane

__global__ __launch_bounds__(256) void k_gather1g2(const int* __restrict__ off,
                                                   const int* __restrict__ esrc,
                                                   const unsigned* __restrict__ h1s2,
                                                   const float* __restrict__ dis,
                                                   const float* __restrict__ b1,
                                                   const float* __restrict__ W2,
                                                   float* __restrict__ h2s) {
    __shared__ float w2l[FH * FC];       // 2 KB
    __shared__ float hrl[16][FH + 2];    // stride 34: conflict-free, float2-aligned
    for (int i = threadIdx.x; i < FH * FC; i += 256) w2l[i] = W2[i];

    int ng = threadIdx.x >> 4;
    int l = threadIdx.x & 15;
    int g = blockIdx.x * 16 + ng;
    int s0 = off[g], s1 = off[g + 1];
    const unsigned* hp = h1s2 + l;  // row stride 16 words
    float ax0 = 0.f, ay0 = 0.f, ax1 = 0.f, ay1 = 0.f;
    float ax2 = 0.f, ay2 = 0.f, ax3 = 0.f, ay3 = 0.f;
    int i = s0;
    for (; i + 3 < s1; i += 4) {
        int r0 = esrc[i], r1 = esrc[i + 1], r2 = esrc[i + 2], r3 = esrc[i + 3];
        unsigned w0 = hp[(size_t)r0 * 16];
        unsigned w1 = hp[(size_t)r1 * 16];
        unsigned w2 = hp[(size_t)r2 * 16];
        unsigned w3 = hp[(size_t)r3 * 16];
        ax0 += bf2f((unsigned short)w0); ay0 += bf2f((unsigned short)(w0 >> 16));
        ax1 += bf2f((unsigned short)w1); ay1 += bf2f((unsigned short)(w1 >> 16));
        ax2 += bf2f((unsigned short)w2); ay2 += bf2f((unsigned short)(w2 >> 16));
        ax3 += bf2f((unsigned short)w3); ay3 += bf2f((unsigned short)(w3 >> 16));
    }
    for (; i < s1; ++i) {
        unsigned w = hp[(size_t)esrc[i] * 16];
        ax0 += bf2f((unsigned short)w); ay0 += bf2f((unsigned short)(w >> 16));
    }
    unsigned ws = hp[(size_t)g * 16];
    float accx = ax0 + ax1 + ax2 + ax3 + bf2f((unsigned short)ws);
    float accy = ay0 + ay1 + ay2 + ay3 + bf2f((unsigned short)(ws >> 16));
    float dg = dis[g];
    float2 bb = ((const float2*)b1)[l];
    float vx = dg * accx + bb.x;
    float vy = dg * accy + bb.y;
    float2 vr = make_float2(vx > 0.f ? vx : 0.f, vy > 0.f ? vy : 0.f);
    *(float2*)&hrl[ng][2 * l] = vr;
    __syncthreads();

    int n2 = threadIdx.x >> 4;
    int j = threadIdx.x & 15;
    int g2 = blockIdx.x * 16 + n2;
    float s = 0.0f;
#pragma unroll
    for (int k = 0; k < FH; ++k) s += hrl[n2][k] * w2l[k * FC + j];
    h2s[(size_t)g2 * FC + j] = s * dis[g2];
}

// ---------------- gather2 (float2 lanes) + log_softmax -> out ----------------
// 32 nodes/block, 8 lanes/node, 2 classes/lane

__global__ __launch_bounds__(256) void k_gather2(const int* __restrict__ off,
                                                 const int* __restrict__ esrc,
                                                 const float* __restrict__ h2s,
                                                 const float* __restrict__ dis,
                                                 const float* __restrict__ b2,
                                                 float* __restrict__ out) {
    int ng = threadIdx.x >> 3;
    int l = threadIdx.x & 7;
    int g = blockIdx.x * 32 + ng;
    int s0 = off[g], s1 = off[g + 1];
    const float2* hp = (const float2*)h2s + l;  // row stride 8 float2
    float ax0 = 0.f, ay0 = 0.f, ax1 = 0.f, ay1 = 0.f;
    float ax2 = 0.f, ay2 = 0.f, ax3 = 0.f, ay3 = 0.f;
    int i = s0;
    for (; i + 3 < s1; i += 4) {
        int r0 = esrc[i], r1 = esrc[i + 1], r2 = esrc[i + 2], r3 = esrc[i + 3];
        float2 t0 = hp[(size_t)r0 * 8];
        float2 t1 = hp[(size_t)r1 * 8];
        float2 t2 = hp[(size_t)r2 * 8];
        float2 t3 = hp[(size_t)r3 * 8];
        ax0 += t0.x; ay0 += t0.y;
        ax1 += t1.x; ay1 += t1.y;
        ax2 += t2.x; ay2 += t2.y;
        ax3 += t3.x; ay3 += t3.y;
    }
    for (; i < s1; ++i) {
        float2 t = hp[(size_t)esrc[i] * 8];
        ax0 += t.x; ay0 += t.y;
    }
    float2 ts = hp[(size_t)g * 8];
    float accx = ax0 + ax1 + ax2 + ax3 + ts.x;
    float accy = ay0 + ay1 + ay2 + ay3 + ts.y;
    float dg = dis[g];
    float2 bb = ((const float2*)b2)[l];
    float vx = dg * accx + bb.x;
    float vy = dg * accy + bb.y;
    float m = fmaxf(vx, vy);
#pragma unroll
    for (int o = 1; o < 8; o <<= 1) m = fmaxf(m, __shfl_xor(m, o, 8));
    float e = __expf(vx - m) + __expf(vy - m);
    float s = e;
#pragma unroll
    for (int o = 1; o < 8; o <<= 1) s += __shfl_xor(s, o, 8);
    float ls = logf(s);
    ((float2*)out)[(size_t)g * 8 + l] = make_float2(vx - m - ls, vy - m - ls);
}

extern "C" void kernel_launch(void* const* d_in, const int* in_sizes, int n_in,
                              void* d_out, int out_size, void* d_ws, size_t ws_size,
                              hipStream_t stream) {
    const float* x  = (const float*)d_in[0];
    const int*   ei = (const int*)d_in[1];
    const float* W1 = (const float*)d_in[2];
    const float* b1 = (const float*)d_in[3];
    const float* W2 = (const float*)d_in[4];
    const float* b2 = (const float*)d_in[5];
    float* out = (float*)d_out;

    const int* row = ei;
    const int* col = ei + NE;

    // workspace layout (int units, ~38 MB; all regions 16B-aligned)
    int* base = (int*)d_ws;
    unsigned char* ghist = (unsigned char*)base;            // M_SL*NN u8 = 3.2M ints
    unsigned char* rank  = ghist + (size_t)M_SL * NN;       // NE u8 = 0.4M ints
    int*   cnt   = base + 3200000 + 400000;                 // NN
    int*   off   = cnt + NN;                                // NN+1 (pad 8)
    int*   part  = off + NN + 8;                            // 128
    float* dis   = (float*)(part + 128);                    // NN
    unsigned short* wbuf = (unsigned short*)(dis + NN);     // 16384 u16 = 8192 ints
    float* h1    = (float*)(wbuf + 16384);                  // NN*FH f32 (3.2M ints)
    unsigned short* h1s = (unsigned short*)(h1 + (size_t)NN * FH);  // NN*FH bf16 (1.6M ints)
    int*   esrc  = (int*)(h1s + (size_t)NN * FH);           // NE
    float* h2s   = h1;                                      // alias: h1 dead after scale

    const int B = 256;

    k_prep<<<1, B, 0, stream>>>(W1, wbuf);
    k_hist_gemm1<<<NGB1 + NHB, B, 0, stream>>>(col, ghist, rank, x, wbuf, h1);
    k_xscan<<<XSB, B, 0, stream>>>((unsigned*)ghist, cnt, dis, part);
    k_scan_off_scale<<<SOS_NB + SCALE_B, 1024, 0, stream>>>(cnt, part, off,
                                                            (const float4*)h1, (ushort4*)h1s, dis);
    k_fill<<<NCB, B, 0, stream>>>(row, col, rank, off, ghist, esrc);
    k_gather1g2<<<NN / 16, B, 0, stream>>>(off, esrc, (const unsigned*)h1s, dis, b1, W2, h2s);
    k_gather2<<<NN / 32, B, 0, stream>>>(off, esrc, h2s, dis, b2, out);
}

// Round 14
// 171.744 us; speedup vs baseline: 1.6333x; 1.0841x over previous
//
#include <hip/hip_runtime.h>
#include <hip/hip_bf16.h>

#define NN 100000
#define NE 1600000
#define FIN 512
#define FH 32
#define FC 16
#define NCB ((NE / 4 + 255) / 256)          // 1563 fill blocks
#define M_SL 32                             // edge slices
#define SLICE (NE / M_SL)                   // 50000 edges/slice
#define QSL (SLICE / 4)                     // 12500 quads/slice
#define PSZ 32768                           // nodes per pass (byte-packed 32 KB LDS)
#define NP ((NN + PSZ - 1) / PSZ)           // 4 passes
#define NHB (M_SL * NP)                     // 128 hist blocks
#define NGB1 ((NN + 63) / 64)               // 1563 MFMA gemm blocks
#define XW (NN / 4)                         // 25000 ghist words per slice
#define XSB ((XW + 255) / 256)              // 98 xscan blocks
#define SOS_NB 98                           // off-scan blocks (1024 nodes each)
#define SCALE_B ((NN * 8 + 1023) / 1024)    // 782 scale blocks (uint2 lanes)

typedef __attribute__((ext_vector_type(8))) short bf16x8;
typedef __attribute__((ext_vector_type(4))) float f32x4;

__device__ inline unsigned short f2bf(float f) {
    unsigned u = __float_as_uint(f);
    return (unsigned short)((u + 0x7FFFu + ((u >> 16) & 1u)) >> 16);  // RNE
}
__device__ inline float bf2f(unsigned short u) {
    return __uint_as_float(((unsigned)u) << 16);
}
__device__ inline unsigned pk2bf(float a, float b) {  // packed 2xbf16 via v_cvt_pk_bf16_f32
    __hip_bfloat162 p = __float22bfloat162_rn(make_float2(a, b));
    union { __hip_bfloat162 h; unsigned u; } c;
    c.h = p;
    return c.u;
}

// ---------------- prep: W1 -> bf16, pre-swizzled to B-fragment order ----------------

__global__ __launch_bounds__(256) void k_prep(const float* __restrict__ W1,
                                              unsigned short* __restrict__ wbuf) {
    for (int idx = threadIdx.x; idx < 16 * 2 * 64; idx += 256) {
        int s = idx >> 7;
        int t = (idx >> 6) & 1;
        int l = idx & 63;
        int k0 = s * 32 + (l >> 4) * 8;
        int c = t * 16 + (l & 15);
        bf16x8 w;
#pragma unroll
        for (int i = 0; i < 8; ++i) w[i] = (short)f2bf(W1[(size_t)(k0 + i) * FH + c]);
        *(bf16x8*)(wbuf + (size_t)idx * 8) = w;
    }
}

// ---------------- fused: MFMA GEMM1 (bf16 permuted out)  +  byte-packed LDS hist ----------------
// h1p layout: row = 16 u32 words; word w packs (col w, col w+16) as 2xbf16.

__global__ __launch_bounds__(256) void k_hist_gemm1(const int* __restrict__ col,
                                                    unsigned char* __restrict__ ghist,
                                                    unsigned char* __restrict__ rank,
                                                    const float* __restrict__ x,
                                                    const unsigned short* __restrict__ wbuf,
                                                    unsigned* __restrict__ h1p) {
    __shared__ int sh[PSZ / 4];  // 32 KB; gemm path reuses as bf16 W store

    if (blockIdx.x >= NGB1) {
        int hb = blockIdx.x - NGB1;
        int p = hb / M_SL;
        int m = hb % M_SL;
        int base = p * PSZ;
        int nb = min(PSZ, NN - base);
        int nw = (nb + 3) >> 2;
        unsigned* shw = (unsigned*)sh;
        for (int i = threadIdx.x; i < nw; i += 256) shw[i] = 0u;
        __syncthreads();
        const int4* c4p = (const int4*)(col + m * SLICE);
        for (int it = 0; it < (QSL + 255) / 256; ++it) {
            int q = it * 256 + threadIdx.x;
            if (q < QSL) {
                int4 c4 = c4p[q];
                int e = m * SLICE + q * 4;
                int cc[4] = {c4.x, c4.y, c4.z, c4.w};
#pragma unroll
                for (int u = 0; u < 4; ++u) {
                    int d = cc[u] - base;
                    if ((unsigned)d < (unsigned)nb) {
                        int sft = 8 * (d & 3);
                        unsigned old = atomicAdd(&shw[d >> 2], 1u << sft);
                        rank[e + u] = (unsigned char)((old >> sft) & 0xFFu);
                    }
                }
            }
        }
        __syncthreads();
        unsigned* gdst = (unsigned*)(ghist + (size_t)m * NN + base);  // 4B-aligned
        for (int i = threadIdx.x; i < nw; i += 256) gdst[i] = shw[i];
        return;
    }

    // ---- MFMA GEMM1 ----
    unsigned short* lb = (unsigned short*)sh;
    for (int i = threadIdx.x; i < 2048; i += 256)
        ((int4*)lb)[i] = ((const int4*)wbuf)[i];  // coalesced 32 KB stage
    __syncthreads();

    int wave = threadIdx.x >> 6;
    int lane = threadIdx.x & 63;
    int rowbase = blockIdx.x * 64 + wave * 16;
    int arow = rowbase + (lane & 15);
    int arowc = min(arow, NN - 1);
    int kgrp = (lane >> 4) * 8;

    f32x4 acc0 = {0.f, 0.f, 0.f, 0.f};
    f32x4 acc1 = {0.f, 0.f, 0.f, 0.f};
    const float* xrow = x + (size_t)arowc * FIN + kgrp;

    for (int sg = 0; sg < 16; sg += 4) {
        float4 av[8];
#pragma unroll
        for (int u = 0; u < 4; ++u) {
            av[2 * u]     = *(const float4*)(xrow + (sg + u) * 32);
            av[2 * u + 1] = *(const float4*)(xrow + (sg + u) * 32 + 4);
        }
#pragma unroll
        for (int u = 0; u < 4; ++u) {
            const float* s0 = (const float*)&av[2 * u];
            const float* s1 = (const float*)&av[2 * u + 1];
            union { bf16x8 v; unsigned w[4]; } af;
            af.w[0] = pk2bf(s0[0], s0[1]);
            af.w[1] = pk2bf(s0[2], s0[3]);
            af.w[2] = pk2bf(s1[0], s1[1]);
            af.w[3] = pk2bf(s1[2], s1[3]);
            int s = sg + u;
            bf16x8 b0 = *(const bf16x8*)(lb + ((size_t)(s * 2 + 0) * 64 + lane) * 8);
            bf16x8 b1 = *(const bf16x8*)(lb + ((size_t)(s * 2 + 1) * 64 + lane) * 8);
            acc0 = __builtin_amdgcn_mfma_f32_16x16x32_bf16(af.v, b0, acc0, 0, 0, 0);
            acc1 = __builtin_amdgcn_mfma_f32_16x16x32_bf16(af.v, b1, acc1, 0, 0, 0);
        }
    }

    int crow = rowbase + (lane >> 4) * 4;
    int ccol = lane & 15;
#pragma unroll
    for (int r = 0; r < 4; ++r) {
        if (crow + r < NN)
            h1p[(size_t)(crow + r) * 16 + ccol] = pk2bf(acc0[r], acc1[r]);
    }
}

// ---------------- SWAR slice-scan: 4 nodes/thread via u32 words ----------------

__global__ __launch_bounds__(256) void k_xscan(unsigned* __restrict__ ghistw,
                                               int* __restrict__ cnt,
                                               float* __restrict__ dis,
                                               int* __restrict__ part) {
    __shared__ int red[256];
    int widx = blockIdx.x * 256 + threadIdx.x;
    int tot = 0;
    if (widx < XW) {
        unsigned s0 = 0, s1 = 0, s2 = 0, s3 = 0;
        unsigned* p = ghistw + widx;
#pragma unroll 4
        for (int m = 0; m < M_SL; ++m) {
            unsigned w = p[(size_t)m * XW];
            p[(size_t)m * XW] = s0 | (s1 << 8) | (s2 << 16) | (s3 << 24);
            s0 += w & 0xFFu; s1 += (w >> 8) & 0xFFu;
            s2 += (w >> 16) & 0xFFu; s3 += (w >> 24) & 0xFFu;
        }
        int c0 = widx * 4;
        *(int4*)(cnt + c0) = make_int4(s0, s1, s2, s3);
        *(float4*)(dis + c0) = make_float4(rsqrtf((float)s0 + 1.f), rsqrtf((float)s1 + 1.f),
                                           rsqrtf((float)s2 + 1.f), rsqrtf((float)s3 + 1.f));
        tot = s0 + s1 + s2 + s3;
    }
    red[threadIdx.x] = tot;
    __syncthreads();
    for (int st = 128; st > 0; st >>= 1) {
        if (threadIdx.x < st) red[threadIdx.x] += red[threadIdx.x + st];
        __syncthreads();
    }
    if (threadIdx.x == 0) part[blockIdx.x] = red[0];
}

// ---------------- fused: off-scan (inline part-scan)  +  h1s = bf16(h1p * dis) ----------------

__global__ __launch_bounds__(1024) void k_scan_off_scale(const int* __restrict__ cnt,
                                                         const int* __restrict__ part,
                                                         int* __restrict__ off,
                                                         const uint2* __restrict__ h1p2,
                                                         uint2* __restrict__ h1s2,
                                                         const float* __restrict__ dis) {
    int bid = blockIdx.x;
    if (bid < SOS_NB) {
        __shared__ int s[1024];
        __shared__ int sp[128];
        if (threadIdx.x < 128) sp[threadIdx.x] = (threadIdx.x < XSB) ? part[threadIdx.x] : 0;
        __syncthreads();
        for (int st = 1; st < 128; st <<= 1) {
            int a = (threadIdx.x < 128 && threadIdx.x >= st) ? sp[threadIdx.x - st] : 0;
            __syncthreads();
            if (threadIdx.x < 128) sp[threadIdx.x] += a;
            __syncthreads();
        }
        int pbase = (bid == 0) ? 0 : sp[bid - 1];
        int i = bid * 1024 + threadIdx.x;
        int v = (i < NN) ? cnt[i] : 0;
        s[threadIdx.x] = v;
        __syncthreads();
        for (int st = 1; st < 1024; st <<= 1) {
            int a = (threadIdx.x >= st) ? s[threadIdx.x - st] : 0;
            __syncthreads();
            s[threadIdx.x] += a;
            __syncthreads();
        }
        if (i < NN) off[i] = pbase + s[threadIdx.x] - v;  // exclusive
        if (i == NN - 1) off[NN] = pbase + s[threadIdx.x];
    } else {
        int idx = (bid - SOS_NB) * 1024 + threadIdx.x;  // uint2 index (4 bf16)
        if (idx < NN * 8) {
            uint2 v = h1p2[idx];
            float d = dis[idx >> 3];
            float a0 = bf2f((unsigned short)v.x), a1 = bf2f((unsigned short)(v.x >> 16));
            float a2 = bf2f((unsigned short)v.y), a3 = bf2f((unsigned short)(v.y >> 16));
            uint2 o;
            o.x = pk2bf(a0 * d, a1 * d);
            o.y = pk2bf(a2 * d, a3 * d);
            h1s2[idx] = o;
        }
    }
}

// ---------------- CSR fill: atomic-free, slot = off[c] + ghist[m][c] + rank ----------------

__global__ void k_fill(const int* __restrict__ row, const int* __restrict__ col,
                       const unsigned char* __restrict__ rank,
                       const int* __restrict__ off,
                       const unsigned char* __restrict__ ghist,
                       int* __restrict__ esrc) {
    int i = blockIdx.x * blockDim.x + threadIdx.x;  // global quad index
    if (i >= NE / 4) return;
    int m = i / QSL;  // slice
    int4 r4 = ((const int4*)row)[i];
    int4 c4 = ((const int4*)col)[i];
    uchar4 rk4 = ((const uchar4*)rank)[i];
    int rr[4] = {r4.x, r4.y, r4.z, r4.w};
    int cc[4] = {c4.x, c4.y, c4.z, c4.w};
    int rk[4] = {rk4.x, rk4.y, rk4.z, rk4.w};
    int o4[4], bp[4];
#pragma unroll
    for (int u = 0; u < 4; ++u) o4[u] = off[cc[u]];
#pragma unroll
    for (int u = 0; u < 4; ++u) bp[u] = ghist[(size_t)m * NN + cc[u]];
#pragma unroll
    for (int u = 0; u < 4; ++u) esrc[o4[u] + bp[u] + rk[u]] = rr[u];
}

// ---------------- gather1 (permuted bf16) + relu + GEMM2: h2s = relu(...)@W2 * dis ----------------
// 16 nodes/block, 16 lanes/node; word l = features (l, l+16)

__global__ __launch_bounds__(256) void k_gather1g2(const int* __restrict__ off,
                                                   const int* __restrict__ esrc,
                                                   const unsigned* __restrict__ h1s,
                                                   const float* __restrict__ dis,
                                                   const float* __restrict__ b1,
                                                   const float* __restrict__ W2,
                                                   float* __restrict__ h2s) {
    __shared__ float w2l[FH * FC];       // 2 KB
    __shared__ float hrl[16][FH + 2];    // stride 34: conflict-free
    for (int i = threadIdx.x; i < FH * FC; i += 256) w2l[i] = W2[i];

    int ng = threadIdx.x >> 4;
    int l = threadIdx.x & 15;
    int g = blockIdx.x * 16 + ng;
    int s0 = off[g], s1 = off[g + 1];
    const unsigned* hp = h1s + l;  // row stride 16 words
    float ax0 = 0.f, ay0 = 0.f, ax1 = 0.f, ay1 = 0.f;
    float ax2 = 0.f, ay2 = 0.f, ax3 = 0.f, ay3 = 0.f;
    int i = s0;
    for (; i + 3 < s1; i += 4) {
        int r0 = esrc[i], r1 = esrc[i + 1], r2 = esrc[i + 2], r3 = esrc[i + 3];
        unsigned w0 = hp[(size_t)r0 * 16];
        unsigned w1 = hp[(size_t)r1 * 16];
        unsigned w2 = hp[(size_t)r2 * 16];
        unsigned w3 = hp[(size_t)r3 * 16];
        ax0 += bf2f((unsigned short)w0); ay0 += bf2f((unsigned short)(w0 >> 16));
        ax1 += bf2f((unsigned short)w1); ay1 += bf2f((unsigned short)(w1 >> 16));
        ax2 += bf2f((unsigned short)w2); ay2 += bf2f((unsigned short)(w2 >> 16));
        ax3 += bf2f((unsigned short)w3); ay3 += bf2f((unsigned short)(w3 >> 16));
    }
    for (; i < s1; ++i) {
        unsigned w = hp[(size_t)esrc[i] * 16];
        ax0 += bf2f((unsigned short)w); ay0 += bf2f((unsigned short)(w >> 16));
    }
    unsigned ws = hp[(size_t)g * 16];
    float accx = ax0 + ax1 + ax2 + ax3 + bf2f((unsigned short)ws);
    float accy = ay0 + ay1 + ay2 + ay3 + bf2f((unsigned short)(ws >> 16));
    float dg = dis[g];
    float vx = dg * accx + b1[l];
    float vy = dg * accy + b1[l + 16];
    hrl[ng][l] = vx > 0.f ? vx : 0.f;
    hrl[ng][l + 16] = vy > 0.f ? vy : 0.f;
    __syncthreads();

    int n2 = threadIdx.x >> 4;
    int j = threadIdx.x & 15;
    int g2 = blockIdx.x * 16 + n2;
    float s = 0.0f;
#pragma unroll
    for (int k = 0; k < FH; ++k) s += hrl[n2][k] * w2l[k * FC + j];
    h2s[(size_t)g2 * FC + j] = s * dis[g2];
}

// ---------------- gather2 (float2 lanes) + log_softmax -> out ----------------
// 32 nodes/block, 8 lanes/node, 2 classes/lane

__global__ __launch_bounds__(256) void k_gather2(const int* __restrict__ off,
                                                 const int* __restrict__ esrc,
                                                 const float* __restrict__ h2s,
                                                 const float* __restrict__ dis,
                                                 const float* __restrict__ b2,
                                                 float* __restrict__ out) {
    int ng = threadIdx.x >> 3;
    int l = threadIdx.x & 7;
    int g = blockIdx.x * 32 + ng;
    int s0 = off[g], s1 = off[g + 1];
    const float2* hp = (const float2*)h2s + l;  // row stride 8 float2
    float ax0 = 0.f, ay0 = 0.f, ax1 = 0.f, ay1 = 0.f;
    float ax2 = 0.f, ay2 = 0.f, ax3 = 0.f, ay3 = 0.f;
    int i = s0;
    for (; i + 3 < s1; i += 4) {
        int r0 = esrc[i], r1 = esrc[i + 1], r2 = esrc[i + 2], r3 = esrc[i + 3];
        float2 t0 = hp[(size_t)r0 * 8];
        float2 t1 = hp[(size_t)r1 * 8];
        float2 t2 = hp[(size_t)r2 * 8];
        float2 t3 = hp[(size_t)r3 * 8];
        ax0 += t0.x; ay0 += t0.y;
        ax1 += t1.x; ay1 += t1.y;
        ax2 += t2.x; ay2 += t2.y;
        ax3 += t3.x; ay3 += t3.y;
    }
    for (; i < s1; ++i) {
        float2 t = hp[(size_t)esrc[i] * 8];
        ax0 += t.x; ay0 += t.y;
    }
    float2 ts = hp[(size_t)g * 8];
    float accx = ax0 + ax1 + ax2 + ax3 + ts.x;
    float accy = ay0 + ay1 + ay2 + ay3 + ts.y;
    float dg = dis[g];
    float2 bb = ((const float2*)b2)[l];
    float vx = dg * accx + bb.x;
    float vy = dg * accy + bb.y;
    float m = fmaxf(vx, vy);
#pragma unroll
    for (int o = 1; o < 8; o <<= 1) m = fmaxf(m, __shfl_xor(m, o, 8));
    float e = __expf(vx - m) + __expf(vy - m);
    float s = e;
#pragma unroll
    for (int o = 1; o < 8; o <<= 1) s += __shfl_xor(s, o, 8);
    float ls = logf(s);
    ((float2*)out)[(size_t)g * 8 + l] = make_float2(vx - m - ls, vy - m - ls);
}

extern "C" void kernel_launch(void* const* d_in, const int* in_sizes, int n_in,
                              void* d_out, int out_size, void* d_ws, size_t ws_size,
                              hipStream_t stream) {
    const float* x  = (const float*)d_in[0];
    const int*   ei = (const int*)d_in[1];
    const float* W1 = (const float*)d_in[2];
    const float* b1 = (const float*)d_in[3];
    const float* W2 = (const float*)d_in[4];
    const float* b2 = (const float*)d_in[5];
    float* out = (float*)d_out;

    const int* row = ei;
    const int* col = ei + NE;

    // workspace layout (int units, ~26 MB; all regions 16B-aligned)
    int* base = (int*)d_ws;
    unsigned char* ghist = (unsigned char*)base;            // M_SL*NN u8 = 800K ints
    unsigned char* rank  = ghist + (size_t)M_SL * NN;       // NE u8 = 400K ints
    int*   cnt   = base + 800000 + 400000;                  // NN
    int*   off   = cnt + NN;                                // NN+1 (pad 8)
    int*   part  = off + NN + 8;                            // 128
    float* dis   = (float*)(part + 128);                    // NN
    unsigned short* wbuf = (unsigned short*)(dis + NN);     // 16384 u16 = 8192 ints
    unsigned* h1p = (unsigned*)(wbuf + 16384);              // NN*16 u32 (1.6M ints)
    unsigned* h1s = h1p + (size_t)NN * 16;                  // NN*16 u32 (1.6M ints)
    int*   esrc  = (int*)(h1s + (size_t)NN * 16);           // NE (1.6M ints)
    float* h2s   = (float*)h1p;                             // alias: h1p dead after scale

    const int B = 256;

    k_prep<<<1, B, 0, stream>>>(W1, wbuf);
    k_hist_gemm1<<<NGB1 + NHB, B, 0, stream>>>(col, ghist, rank, x, wbuf, h1p);
    k_xscan<<<XSB, B, 0, stream>>>((unsigned*)ghist, cnt, dis, part);
    k_scan_off_scale<<<SOS_NB + SCALE_B, 1024, 0, stream>>>(cnt, part, off,
                                                            (const uint2*)h1p, (uint2*)h1s, dis);
    k_fill<<<NCB, B, 0, stream>>>(row, col, rank, off, ghist, esrc);
    k_gather1g2<<<NN / 16, B, 0, stream>>>(off, esrc, h1s, dis, b1, W2, h2s);
    k_gather2<<<NN / 32, B, 0, stream>>>(off, esrc, h2s, dis, b2, out);
}

// Round 15
// 168.137 us; speedup vs baseline: 1.6683x; 1.0215x over previous
//
#include <hip/hip_runtime.h>
#include <hip/hip_bf16.h>

#define NN 100000
#define NE 1600000
#define FIN 512
#define FH 32
#define FC 16
#define NCB2 ((NE / 8 + 255) / 256)         // 782 fill blocks (8 edges/thread)
#define M_SL 32                             // edge slices
#define SLICE (NE / M_SL)                   // 50000 edges/slice
#define QSL (SLICE / 4)                     // 12500 quads/slice
#define PSZ 32768                           // nodes per pass (byte-packed 32 KB LDS)
#define NP ((NN + PSZ - 1) / PSZ)           // 4 passes
#define NHB (M_SL * NP)                     // 128 hist blocks
#define NGB1 ((NN + 63) / 64)               // 1563 MFMA gemm blocks
#define XW (NN / 4)                         // 25000 ghist words per slice
#define XSB ((XW + 255) / 256)              // 98 xscan blocks
#define SOS_NB 98                           // off-scan blocks (1024 nodes each)
#define SCALE_B ((NN * 8 + 1023) / 1024)    // 782 scale blocks (uint2 lanes)

typedef __attribute__((ext_vector_type(8))) short bf16x8;
typedef __attribute__((ext_vector_type(4))) float f32x4;

__device__ inline unsigned short f2bf(float f) {
    unsigned u = __float_as_uint(f);
    return (unsigned short)((u + 0x7FFFu + ((u >> 16) & 1u)) >> 16);  // RNE
}
__device__ inline float bf2f(unsigned short u) {
    return __uint_as_float(((unsigned)u) << 16);
}
__device__ inline unsigned pk2bf(float a, float b) {  // packed 2xbf16 via v_cvt_pk_bf16_f32
    __hip_bfloat162 p = __float22bfloat162_rn(make_float2(a, b));
    union { __hip_bfloat162 h; unsigned u; } c;
    c.h = p;
    return c.u;
}

// ---------------- prep: W1 -> bf16, pre-swizzled to B-fragment order ----------------

__global__ __launch_bounds__(256) void k_prep(const float* __restrict__ W1,
                                              unsigned short* __restrict__ wbuf) {
    for (int idx = threadIdx.x; idx < 16 * 2 * 64; idx += 256) {
        int s = idx >> 7;
        int t = (idx >> 6) & 1;
        int l = idx & 63;
        int k0 = s * 32 + (l >> 4) * 8;
        int c = t * 16 + (l & 15);
        bf16x8 w;
#pragma unroll
        for (int i = 0; i < 8; ++i) w[i] = (short)f2bf(W1[(size_t)(k0 + i) * FH + c]);
        *(bf16x8*)(wbuf + (size_t)idx * 8) = w;
    }
}

// ---------------- fused: MFMA GEMM1 (bf16 permuted out)  +  byte-packed LDS hist ----------------
// h1p layout: row = 16 u32 words; word w packs (col w, col w+16) as 2xbf16.

__global__ __launch_bounds__(256) void k_hist_gemm1(const int* __restrict__ col,
                                                    unsigned char* __restrict__ ghist,
                                                    unsigned char* __restrict__ rank,
                                                    const float* __restrict__ x,
                                                    const unsigned short* __restrict__ wbuf,
                                                    unsigned* __restrict__ h1p) {
    __shared__ int sh[PSZ / 4];  // 32 KB; gemm path reuses as bf16 W store

    if (blockIdx.x >= NGB1) {
        int hb = blockIdx.x - NGB1;
        int p = hb / M_SL;
        int m = hb % M_SL;
        int base = p * PSZ;
        int nb = min(PSZ, NN - base);
        int nw = (nb + 3) >> 2;
        unsigned* shw = (unsigned*)sh;
        for (int i = threadIdx.x; i < nw; i += 256) shw[i] = 0u;
        __syncthreads();
        const int4* c4p = (const int4*)(col + m * SLICE);
        for (int it = 0; it < (QSL + 255) / 256; ++it) {
            int q = it * 256 + threadIdx.x;
            if (q < QSL) {
                int4 c4 = c4p[q];
                int e = m * SLICE + q * 4;
                int cc[4] = {c4.x, c4.y, c4.z, c4.w};
#pragma unroll
                for (int u = 0; u < 4; ++u) {
                    int d = cc[u] - base;
                    if ((unsigned)d < (unsigned)nb) {
                        int sft = 8 * (d & 3);
                        unsigned old = atomicAdd(&shw[d >> 2], 1u << sft);
                        rank[e + u] = (unsigned char)((old >> sft) & 0xFFu);
                    }
                }
            }
        }
        __syncthreads();
        unsigned* gdst = (unsigned*)(ghist + (size_t)m * NN + base);  // 4B-aligned
        for (int i = threadIdx.x; i < nw; i += 256) gdst[i] = shw[i];
        return;
    }

    // ---- MFMA GEMM1 ----
    unsigned short* lb = (unsigned short*)sh;
    for (int i = threadIdx.x; i < 2048; i += 256)
        ((int4*)lb)[i] = ((const int4*)wbuf)[i];  // coalesced 32 KB stage
    __syncthreads();

    int wave = threadIdx.x >> 6;
    int lane = threadIdx.x & 63;
    int rowbase = blockIdx.x * 64 + wave * 16;
    int arow = rowbase + (lane & 15);
    int arowc = min(arow, NN - 1);
    int kgrp = (lane >> 4) * 8;

    f32x4 acc0 = {0.f, 0.f, 0.f, 0.f};
    f32x4 acc1 = {0.f, 0.f, 0.f, 0.f};
    const float* xrow = x + (size_t)arowc * FIN + kgrp;

    for (int sg = 0; sg < 16; sg += 4) {
        float4 av[8];
#pragma unroll
        for (int u = 0; u < 4; ++u) {
            av[2 * u]     = *(const float4*)(xrow + (sg + u) * 32);
            av[2 * u + 1] = *(const float4*)(xrow + (sg + u) * 32 + 4);
        }
#pragma unroll
        for (int u = 0; u < 4; ++u) {
            const float* s0 = (const float*)&av[2 * u];
            const float* s1 = (const float*)&av[2 * u + 1];
            union { bf16x8 v; unsigned w[4]; } af;
            af.w[0] = pk2bf(s0[0], s0[1]);
            af.w[1] = pk2bf(s0[2], s0[3]);
            af.w[2] = pk2bf(s1[0], s1[1]);
            af.w[3] = pk2bf(s1[2], s1[3]);
            int s = sg + u;
            bf16x8 b0 = *(const bf16x8*)(lb + ((size_t)(s * 2 + 0) * 64 + lane) * 8);
            bf16x8 b1 = *(const bf16x8*)(lb + ((size_t)(s * 2 + 1) * 64 + lane) * 8);
            acc0 = __builtin_amdgcn_mfma_f32_16x16x32_bf16(af.v, b0, acc0, 0, 0, 0);
            acc1 = __builtin_amdgcn_mfma_f32_16x16x32_bf16(af.v, b1, acc1, 0, 0, 0);
        }
    }

    int crow = rowbase + (lane >> 4) * 4;
    int ccol = lane & 15;
#pragma unroll
    for (int r = 0; r < 4; ++r) {
        if (crow + r < NN)
            h1p[(size_t)(crow + r) * 16 + ccol] = pk2bf(acc0[r], acc1[r]);
    }
}

// ---------------- SWAR slice-scan: 4 nodes/thread via u32 words ----------------

__global__ __launch_bounds__(256) void k_xscan(unsigned* __restrict__ ghistw,
                                               int* __restrict__ cnt,
                                               float* __restrict__ dis,
                                               int* __restrict__ part) {
    __shared__ int red[256];
    int widx = blockIdx.x * 256 + threadIdx.x;
    int tot = 0;
    if (widx < XW) {
        unsigned s0 = 0, s1 = 0, s2 = 0, s3 = 0;
        unsigned* p = ghistw + widx;
#pragma unroll 4
        for (int m = 0; m < M_SL; ++m) {
            unsigned w = p[(size_t)m * XW];
            p[(size_t)m * XW] = s0 | (s1 << 8) | (s2 << 16) | (s3 << 24);
            s0 += w & 0xFFu; s1 += (w >> 8) & 0xFFu;
            s2 += (w >> 16) & 0xFFu; s3 += (w >> 24) & 0xFFu;
        }
        int c0 = widx * 4;
        *(int4*)(cnt + c0) = make_int4(s0, s1, s2, s3);
        *(float4*)(dis + c0) = make_float4(rsqrtf((float)s0 + 1.f), rsqrtf((float)s1 + 1.f),
                                           rsqrtf((float)s2 + 1.f), rsqrtf((float)s3 + 1.f));
        tot = s0 + s1 + s2 + s3;
    }
    red[threadIdx.x] = tot;
    __syncthreads();
    for (int st = 128; st > 0; st >>= 1) {
        if (threadIdx.x < st) red[threadIdx.x] += red[threadIdx.x + st];
        __syncthreads();
    }
    if (threadIdx.x == 0) part[blockIdx.x] = red[0];
}

// ---------------- fused: off-scan (inline part-scan)  +  h1s = bf16(h1p * dis) ----------------

__global__ __launch_bounds__(1024) void k_scan_off_scale(const int* __restrict__ cnt,
                                                         const int* __restrict__ part,
                                                         int* __restrict__ off,
                                                         const uint2* __restrict__ h1p2,
                                                         uint2* __restrict__ h1s2,
                                                         const float* __restrict__ dis) {
    int bid = blockIdx.x;
    if (bid < SOS_NB) {
        __shared__ int s[1024];
        __shared__ int sp[128];
        if (threadIdx.x < 128) sp[threadIdx.x] = (threadIdx.x < XSB) ? part[threadIdx.x] : 0;
        __syncthreads();
        for (int st = 1; st < 128; st <<= 1) {
            int a = (threadIdx.x < 128 && threadIdx.x >= st) ? sp[threadIdx.x - st] : 0;
            __syncthreads();
            if (threadIdx.x < 128) sp[threadIdx.x] += a;
            __syncthreads();
        }
        int pbase = (bid == 0) ? 0 : sp[bid - 1];
        int i = bid * 1024 + threadIdx.x;
        int v = (i < NN) ? cnt[i] : 0;
        s[threadIdx.x] = v;
        __syncthreads();
        for (int st = 1; st < 1024; st <<= 1) {
            int a = (threadIdx.x >= st) ? s[threadIdx.x - st] : 0;
            __syncthreads();
            s[threadIdx.x] += a;
            __syncthreads();
        }
        if (i < NN) off[i] = pbase + s[threadIdx.x] - v;  // exclusive
        if (i == NN - 1) off[NN] = pbase + s[threadIdx.x];
    } else {
        int idx = (bid - SOS_NB) * 1024 + threadIdx.x;  // uint2 index (4 bf16)
        if (idx < NN * 8) {
            uint2 v = h1p2[idx];
            float d = dis[idx >> 3];
            float a0 = bf2f((unsigned short)v.x), a1 = bf2f((unsigned short)(v.x >> 16));
            float a2 = bf2f((unsigned short)v.y), a3 = bf2f((unsigned short)(v.y >> 16));
            uint2 o;
            o.x = pk2bf(a0 * d, a1 * d);
            o.y = pk2bf(a2 * d, a3 * d);
            h1s2[idx] = o;
        }
    }
}

// ---------------- CSR fill: atomic-free, 8 edges/thread ----------------

__global__ void k_fill(const int* __restrict__ row, const int* __restrict__ col,
                       const unsigned char* __restrict__ rank,
                       const int* __restrict__ off,
                       const unsigned char* __restrict__ ghist,
                       int* __restrict__ esrc) {
    int t = blockIdx.x * blockDim.x + threadIdx.x;
    if (t >= NE / 8) return;
#pragma unroll
    for (int qq = 0; qq < 2; ++qq) {
        int i = t * 2 + qq;  // quad index
        int m = i / QSL;     // slice
        int4 r4 = ((const int4*)row)[i];
        int4 c4 = ((const int4*)col)[i];
        uchar4 rk4 = ((const uchar4*)rank)[i];
        int rr[4] = {r4.x, r4.y, r4.z, r4.w};
        int cc[4] = {c4.x, c4.y, c4.z, c4.w};
        int rk[4] = {rk4.x, rk4.y, rk4.z, rk4.w};
        int o4[4], bp[4];
#pragma unroll
        for (int u = 0; u < 4; ++u) o4[u] = off[cc[u]];
#pragma unroll
        for (int u = 0; u < 4; ++u) bp[u] = ghist[(size_t)m * NN + cc[u]];
#pragma unroll
        for (int u = 0; u < 4; ++u) esrc[o4[u] + bp[u] + rk[u]] = rr[u];
    }
}

// ---------------- gather1 (uint2 lanes) + relu + GEMM2: h2s = relu(...)@W2 * dis ----------------
// 32 nodes/block, 8 lanes/node; lane l owns words {2l, 2l+1} = features (2l, 2l+16, 2l+1, 2l+17)

__global__ __launch_bounds__(256) void k_gather1g2(const int* __restrict__ off,
                                                   const int* __restrict__ esrc,
                                                   const unsigned* __restrict__ h1s,
                                                   const float* __restrict__ dis,
                                                   const float* __restrict__ b1,
                                                   const float* __restrict__ W2,
                                                   float* __restrict__ h2s) {
    __shared__ float w2l[FH * FC];       // 2 KB
    __shared__ float hrl[32][FH + 2];    // stride 34 (even): conflict-free, float2-aligned
    for (int i = threadIdx.x; i < FH * FC; i += 256) w2l[i] = W2[i];

    int ng = threadIdx.x >> 3;
    int l = threadIdx.x & 7;
    int g = blockIdx.x * 32 + ng;
    int s0 = off[g], s1 = off[g + 1];
    const uint2* hp = (const uint2*)h1s + l;  // row stride 8 uint2
    float a00 = 0.f, a01 = 0.f, a02 = 0.f, a03 = 0.f;
    float a10 = 0.f, a11 = 0.f, a12 = 0.f, a13 = 0.f;
    float a20 = 0.f, a21 = 0.f, a22 = 0.f, a23 = 0.f;
    float a30 = 0.f, a31 = 0.f, a32 = 0.f, a33 = 0.f;
    int i = s0;
    for (; i + 3 < s1; i += 4) {
        int r0 = esrc[i], r1 = esrc[i + 1], r2 = esrc[i + 2], r3 = esrc[i + 3];
        uint2 w0 = hp[(size_t)r0 * 8];
        uint2 w1 = hp[(size_t)r1 * 8];
        uint2 w2 = hp[(size_t)r2 * 8];
        uint2 w3 = hp[(size_t)r3 * 8];
        a00 += bf2f((unsigned short)w0.x); a01 += bf2f((unsigned short)(w0.x >> 16));
        a02 += bf2f((unsigned short)w0.y); a03 += bf2f((unsigned short)(w0.y >> 16));
        a10 += bf2f((unsigned short)w1.x); a11 += bf2f((unsigned short)(w1.x >> 16));
        a12 += bf2f((unsigned short)w1.y); a13 += bf2f((unsigned short)(w1.y >> 16));
        a20 += bf2f((unsigned short)w2.x); a21 += bf2f((unsigned short)(w2.x >> 16));
        a22 += bf2f((unsigned short)w2.y); a23 += bf2f((unsigned short)(w2.y >> 16));
        a30 += bf2f((unsigned short)w3.x); a31 += bf2f((unsigned short)(w3.x >> 16));
        a32 += bf2f((unsigned short)w3.y); a33 += bf2f((unsigned short)(w3.y >> 16));
    }
    for (; i < s1; ++i) {
        uint2 w = hp[(size_t)esrc[i] * 8];
        a00 += bf2f((unsigned short)w.x); a01 += bf2f((unsigned short)(w.x >> 16));
        a02 += bf2f((unsigned short)w.y); a03 += bf2f((unsigned short)(w.y >> 16));
    }
    uint2 ws = hp[(size_t)g * 8];
    float f0 = a00 + a10 + a20 + a30 + bf2f((unsigned short)ws.x);   // feature 2l
    float f16 = a01 + a11 + a21 + a31 + bf2f((unsigned short)(ws.x >> 16));  // 2l+16
    float f1 = a02 + a12 + a22 + a32 + bf2f((unsigned short)ws.y);   // 2l+1
    float f17 = a03 + a13 + a23 + a33 + bf2f((unsigned short)(ws.y >> 16)); // 2l+17
    float dg = dis[g];
    float2 blo = ((const float2*)b1)[l];       // b1[2l], b1[2l+1]
    float2 bhi = ((const float2*)b1)[l + 8];   // b1[2l+16], b1[2l+17]
    float v0 = dg * f0 + blo.x;
    float v1 = dg * f1 + blo.y;
    float v16 = dg * f16 + bhi.x;
    float v17 = dg * f17 + bhi.y;
    *(float2*)&hrl[ng][2 * l] = make_float2(v0 > 0.f ? v0 : 0.f, v1 > 0.f ? v1 : 0.f);
    *(float2*)&hrl[ng][2 * l + 16] = make_float2(v16 > 0.f ? v16 : 0.f, v17 > 0.f ? v17 : 0.f);
    __syncthreads();

    int j = threadIdx.x & 15;
#pragma unroll
    for (int half = 0; half < 2; ++half) {
        int n2 = (threadIdx.x >> 4) + half * 16;
        int g2 = blockIdx.x * 32 + n2;
        float s = 0.0f;
#pragma unroll
        for (int k = 0; k < FH; ++k) s += hrl[n2][k] * w2l[k * FC + j];
        h2s[(size_t)g2 * FC + j] = s * dis[g2];
    }
}

// ---------------- gather2 (float4 lanes) + log_softmax -> out ----------------
// 64 nodes/block, 4 lanes/node, 4 classes/lane

__global__ __launch_bounds__(256) void k_gather2(const int* __restrict__ off,
                                                 const int* __restrict__ esrc,
                                                 const float* __restrict__ h2s,
                                                 const float* __restrict__ dis,
                                                 const float* __restrict__ b2,
                                                 float* __restrict__ out) {
    int ng = threadIdx.x >> 2;
    int l = threadIdx.x & 3;
    int g = blockIdx.x * 64 + ng;
    if (g >= NN) return;
    int s0 = off[g], s1 = off[g + 1];
    const float4* hp = (const float4*)h2s + l;  // row stride 4 float4
    float ax0 = 0.f, ay0 = 0.f, az0 = 0.f, aw0 = 0.f;
    float ax1 = 0.f, ay1 = 0.f, az1 = 0.f, aw1 = 0.f;
    float ax2 = 0.f, ay2 = 0.f, az2 = 0.f, aw2 = 0.f;
    float ax3 = 0.f, ay3 = 0.f, az3 = 0.f, aw3 = 0.f;
    int i = s0;
    for (; i + 3 < s1; i += 4) {
        int r0 = esrc[i], r1 = esrc[i + 1], r2 = esrc[i + 2], r3 = esrc[i + 3];
        float4 t0 = hp[(size_t)r0 * 4];
        float4 t1 = hp[(size_t)r1 * 4];
        float4 t2 = hp[(size_t)r2 * 4];
        float4 t3 = hp[(size_t)r3 * 4];
        ax0 += t0.x; ay0 += t0.y; az0 += t0.z; aw0 += t0.w;
        ax1 += t1.x; ay1 += t1.y; az1 += t1.z; aw1 += t1.w;
        ax2 += t2.x; ay2 += t2.y; az2 += t2.z; aw2 += t2.w;
        ax3 += t3.x; ay3 += t3.y; az3 += t3.z; aw3 += t3.w;
    }
    for (; i < s1; ++i) {
        float4 t = hp[(size_t)esrc[i] * 4];
        ax0 += t.x; ay0 += t.y; az0 += t.z; aw0 += t.w;
    }
    float4 ts = hp[(size_t)g * 4];
    float vx = ax0 + ax1 + ax2 + ax3 + ts.x;
    float vy = ay0 + ay1 + ay2 + ay3 + ts.y;
    float vz = az0 + az1 + az2 + az3 + ts.z;
    float vw = aw0 + aw1 + aw2 + aw3 + ts.w;
    float dg = dis[g];
    float4 bb = ((const float4*)b2)[l];
    vx = dg * vx + bb.x;
    vy = dg * vy + bb.y;
    vz = dg * vz + bb.z;
    vw = dg * vw + bb.w;
    float m = fmaxf(fmaxf(vx, vy), fmaxf(vz, vw));
#pragma unroll
    for (int o = 1; o < 4; o <<= 1) m = fmaxf(m, __shfl_xor(m, o, 4));
    float e = __expf(vx - m) + __expf(vy - m) + __expf(vz - m) + __expf(vw - m);
    float s = e;
#pragma unroll
    for (int o = 1; o < 4; o <<= 1) s += __shfl_xor(s, o, 4);
    float ls = m + logf(s);
    ((float4*)out)[(size_t)g * 4 + l] = make_float4(vx - ls, vy - ls, vz - ls, vw - ls);
}

extern "C" void kernel_launch(void* const* d_in, const int* in_sizes, int n_in,
                              void* d_out, int out_size, void* d_ws, size_t ws_size,
                              hipStream_t stream) {
    const float* x  = (const float*)d_in[0];
    const int*   ei = (const int*)d_in[1];
    const float* W1 = (const float*)d_in[2];
    const float* b1 = (const float*)d_in[3];
    const float* W2 = (const float*)d_in[4];
    const float* b2 = (const float*)d_in[5];
    float* out = (float*)d_out;

    const int* row = ei;
    const int* col = ei + NE;

    // workspace layout (int units, ~26 MB; all regions 16B-aligned)
    int* base = (int*)d_ws;
    unsigned char* ghist = (unsigned char*)base;            // M_SL*NN u8 = 800K ints
    unsigned char* rank  = ghist + (size_t)M_SL * NN;       // NE u8 = 400K ints
    int*   cnt   = base + 800000 + 400000;                  // NN
    int*   off   = cnt + NN;                                // NN+1 (pad 8)
    int*   part  = off + NN + 8;                            // 128
    float* dis   = (float*)(part + 128);                    // NN
    unsigned short* wbuf = (unsigned short*)(dis + NN);     // 16384 u16 = 8192 ints
    unsigned* h1p = (unsigned*)(wbuf + 16384);              // NN*16 u32 (1.6M ints)
    unsigned* h1s = h1p + (size_t)NN * 16;                  // NN*16 u32 (1.6M ints)
    int*   esrc  = (int*)(h1s + (size_t)NN * 16);           // NE (1.6M ints)
    float* h2s   = (float*)h1p;                             // alias: h1p dead after scale

    const int B = 256;

    k_prep<<<1, B, 0, stream>>>(W1, wbuf);
    k_hist_gemm1<<<NGB1 + NHB, B, 0, stream>>>(col, ghist, rank, x, wbuf, h1p);
    k_xscan<<<XSB, B, 0, stream>>>((unsigned*)ghist, cnt, dis, part);
    k_scan_off_scale<<<SOS_NB + SCALE_B, 1024, 0, stream>>>(cnt, part, off,
                                                            (const uint2*)h1p, (uint2*)h1s, dis);
    k_fill<<<NCB2, B, 0, stream>>>(row, col, rank, off, ghist, esrc);
    k_gather1g2<<<NN / 32, B, 0, stream>>>(off, esrc, h1s, dis, b1, W2, h2s);
    k_gather2<<<(NN + 63) / 64, B, 0, stream>>>(off, esrc, h2s, dis, b2, out);
}